// Round 6
// baseline (547.118 us; speedup 1.0000x reference)
//
#include <hip/hip_runtime.h>
#include <hip/hip_bf16.h>

#define B_     8
#define C_IN   64
#define C_OUT  128
#define HW     256
#define NK     8
#define KS     3

typedef __attribute__((ext_vector_type(8))) short bf16x8;
typedef __attribute__((ext_vector_type(4))) float f32x4;
typedef __attribute__((ext_vector_type(4))) unsigned int u32x4;

__device__ inline unsigned short f2bf(float f) {
    union { float f; unsigned int u; } a; a.f = f;
    unsigned int u = a.u;
    u += 0x7fffu + ((u >> 16) & 1u);   // round-to-nearest-even
    return (unsigned short)(u >> 16);
}
__device__ inline float bf2f(unsigned short u) {
    union { float f; unsigned int u; } a; a.u = ((unsigned int)u) << 16; return a.f;
}

// xT geometry: [b][hp=258][r=258][c=64] bf16, hp = h+1, r = w+1, zero-padded
// borders. Within each 128-B row the 16-B chunk holding channels 8j..8j+7 is
// stored at slot (j ^ (r & 7)) -> conv's ds_read_b128 is bank-balanced while
// global_load_lds stays a linear copy (swizzle pre-baked in global memory).
#define XT_PLANE  (258 * 64)            /* shorts per (b,hp) plane */
#define SLAB_B    16640                 /* bytes per staged slab: 130 rows x 128 B */

// ---------------------------------------------------------------------------
// Prepass: x fp32 -> swizzled bf16 xT, per-(b,hp) pool partials to scratch.
// grid (258, 8) x 256.
// ---------------------------------------------------------------------------
__global__ __launch_bounds__(256) void prepass_kernel(const float* __restrict__ x,
                                                      unsigned short* __restrict__ xT,
                                                      float* __restrict__ poolpart) {
    const int hp = blockIdx.x;          // 0..257
    const int b  = blockIdx.y;
    const int t  = threadIdx.x;
    unsigned short* plane = xT + ((size_t)b * 258 + hp) * XT_PLANE;

    if (hp == 0 || hp == 257) {         // h-halo planes: all zero
        f32x4 z = {0.f, 0.f, 0.f, 0.f};
        for (int ofs = t * 16; ofs < XT_PLANE * 2; ofs += 256 * 16)
            *(f32x4*)((char*)plane + ofs) = z;
        return;
    }
    const int h = hp - 1;

    __shared__ unsigned short tile[256 * 66];   // [w][c], stride 66 (bank-clean)
    __shared__ float psum[4][64];

    const float* xp = x + ((size_t)b * C_IN * HW + h) * HW + t;   // c=0, w=t
    unsigned int pk[32];
    #pragma unroll
    for (int ci = 0; ci < 32; ci++) {
        float v0 = xp[(size_t)(2 * ci) * (HW * HW)];
        float v1 = xp[(size_t)(2 * ci + 1) * (HW * HW)];
        unsigned int p = (unsigned int)f2bf(v0) | ((unsigned int)f2bf(v1) << 16);
        pk[ci] = p;
        *(unsigned int*)&tile[t * 66 + 2 * ci] = p;
    }

    // swizzled store of row r = t+1
    unsigned short* rowp = plane + (size_t)(t + 1) * 64;
    const int sw = (t + 1) & 7;
    #pragma unroll
    for (int j = 0; j < 8; j++) {
        u32x4 v; v[0] = pk[4*j]; v[1] = pk[4*j+1]; v[2] = pk[4*j+2]; v[3] = pk[4*j+3];
        *(u32x4*)(rowp + (size_t)((j ^ sw) * 8)) = v;
    }
    if (t < 2) {                        // w-halo rows r=0 and r=257: zero
        unsigned short* zr = plane + (size_t)(t ? 257 : 0) * 64;
        f32x4 z = {0.f, 0.f, 0.f, 0.f};
        #pragma unroll
        for (int j = 0; j < 8; j++) *(f32x4*)((char*)zr + j * 16) = z;
    }

    // pool partials: transpose-reduce over w, one row per (b,hp)
    __syncthreads();
    const int c = t & 63, part = t >> 6;
    float s = 0.f;
    #pragma unroll 8
    for (int i = 0; i < 64; i++)
        s += bf2f(tile[(part * 64 + i) * 66 + c]);
    psum[part][c] = s;
    __syncthreads();
    if (t < 64)
        poolpart[((size_t)b * 258 + hp) * 64 + t] =
            (psum[0][t] + psum[1][t]) + (psum[2][t] + psum[3][t]);
}

// ---------------------------------------------------------------------------
// Pool-reduce + logits + softmax.  grid B_ blocks x 256 threads.
// ---------------------------------------------------------------------------
__global__ __launch_bounds__(256) void attn_kernel(const float* __restrict__ poolpart,
                                                   const float* __restrict__ attn_w,
                                                   const float* __restrict__ attn_b,
                                                   float* __restrict__ attn) {
    const int b = blockIdx.x;
    const int t = threadIdx.x;
    const int c = t & 63, part = t >> 6;
    __shared__ float psum[4][64];
    __shared__ float pooled[64];
    __shared__ float logits[NK];

    float s = 0.f;
    const float* pp = poolpart + ((size_t)b * 258) * 64 + c;
    for (int hp = part * 64 + 1; hp <= part * 64 + 64; hp++)
        s += pp[(size_t)hp * 64];
    psum[part][c] = s;
    __syncthreads();
    if (t < 64)
        pooled[t] = ((psum[0][t] + psum[1][t]) + (psum[2][t] + psum[3][t]))
                    * (1.0f / (HW * HW));
    __syncthreads();
    if (t < NK) {
        float l = attn_b[t];
        #pragma unroll 8
        for (int cc = 0; cc < C_IN; cc++) l += pooled[cc] * attn_w[t * C_IN + cc];
        logits[t] = l;
    }
    __syncthreads();
    if (t < NK) {
        float m = -1e30f;
        #pragma unroll
        for (int j = 0; j < NK; j++) m = fmaxf(m, logits[j]);
        float denom = 0.f;
        #pragma unroll
        for (int j = 0; j < NK; j++) denom += expf(logits[j] - m);
        attn[b * NK + t] = expf(logits[t] - m) / denom;
    }
}

// ---------------------------------------------------------------------------
// mixed weights -> bf16, pre-swizzled into MFMA A-fragment order:
//   Wt2[b][kh][kw][ic][o][di]  (ic = i>>5, di = i&31)
// ---------------------------------------------------------------------------
__global__ __launch_bounds__(256) void mix_kernel(const float* __restrict__ bank,
                                                  const float* __restrict__ attn,
                                                  unsigned short* __restrict__ Wt2) {
    const int PER_B = C_OUT * C_IN * KS * KS;   // 73728
    int idx = blockIdx.x * 256 + threadIdx.x;
    int b = idx / PER_B;
    int r = idx % PER_B;
    float s = 0.f;
    #pragma unroll
    for (int n = 0; n < NK; n++) s += attn[b * NK + n] * bank[(size_t)n * PER_B + r];
    int kw = r % 3;
    int t1 = r / 3;
    int kh = t1 % 3;
    int t2 = t1 / 3;
    int i = t2 & 63;
    int o = t2 >> 6;
    size_t off = (((size_t)((b * 3 + kh) * 3 + kw) * 2 + (i >> 5)) * 128 + o) * 32 + (i & 31);
    Wt2[off] = f2bf(s);
}

// ---------------------------------------------------------------------------
// Conv v8: EXACT conv2 (round-1, best measured) structure -- 4 waves, 64x64
// wave tile, 4-slab ring, STAGE/vmcnt(5)/barriers identical -- plus ONE
// change: the 18 (kh,kw,ic) K-steps are flattened and software-pipelined
// 1-deep in plain HIP. Step s issues step s+1's 4 A-loads (global/L2) and
// 4 B ds_reads into the idle ping-pong register set, then runs step s's 16
// MFMAs. All register indices are compile-time (two named sets, unrolled
// parity), so no scratch. Compiler inserts the counted waits.
// ---------------------------------------------------------------------------
__global__ __launch_bounds__(256, 2) void conv_mfma8(const unsigned short* __restrict__ xT,
                                                     const short* __restrict__ Wt2,
                                                     float* __restrict__ out) {
    const int w0 = blockIdx.x * 128;   // 0 or 128
    const int h0 = blockIdx.y * 8;
    const int b  = blockIdx.z;

    const int t    = threadIdx.x;
    const int lane = t & 63;
    const int wid  = t >> 6;
    const int wm   = (wid & 1) * 64;   // wave M offset
    const int wn   = (wid >> 1) * 64;  // wave N offset
    const int l15  = lane & 15;
    const int quad = lane >> 4;

    __shared__ short sxs[4 * 8320];     // 4 ring slabs x 16640 B

    #define STAGE(HP) do {                                                            \
        const char* _src = (const char*)(xT + (((size_t)b * 258 + (size_t)(HP)) * 258 \
                                               + (size_t)w0) * 64);                   \
        char* _dst = (char*)sxs + (((HP) & 3) * SLAB_B);                              \
        const int _wo = wid * 4096;                                                   \
        __builtin_amdgcn_global_load_lds((const __attribute__((address_space(1))) void*)(_src + _wo +        lane * 16), (__attribute__((address_space(3))) void*)(_dst + _wo),        16, 0, 0); \
        __builtin_amdgcn_global_load_lds((const __attribute__((address_space(1))) void*)(_src + _wo + 1024 + lane * 16), (__attribute__((address_space(3))) void*)(_dst + _wo + 1024), 16, 0, 0); \
        __builtin_amdgcn_global_load_lds((const __attribute__((address_space(1))) void*)(_src + _wo + 2048 + lane * 16), (__attribute__((address_space(3))) void*)(_dst + _wo + 2048), 16, 0, 0); \
        __builtin_amdgcn_global_load_lds((const __attribute__((address_space(1))) void*)(_src + _wo + 3072 + lane * 16), (__attribute__((address_space(3))) void*)(_dst + _wo + 3072), 16, 0, 0); \
        __builtin_amdgcn_global_load_lds((const __attribute__((address_space(1))) void*)(_src + 16384 + lane * 4),       (__attribute__((address_space(3))) void*)(_dst + 16384),        4, 0, 0); \
    } while (0)

    // load operands of flat step S into named register sets AV[4], BV[4]
    #define LOADSTEP(S, AV, BV) do {                                                  \
        const int kh_ = (S) / 6, kw_ = ((S) % 6) >> 1, ic_ = (S) & 1;                 \
        const short* Ap_ = Abase + (S) * 4096;                                        \
        AV##0 = *(const bf16x8*)(Ap_);                                                \
        AV##1 = *(const bf16x8*)(Ap_ + 512);                                          \
        AV##2 = *(const bf16x8*)(Ap_ + 1024);                                         \
        AV##3 = *(const bf16x8*)(Ap_ + 1536);                                         \
        const short* buf_ = sxs + ((h + kh_) & 3) * 8320;                             \
        const int row_ = wn + l15 + kw_;                                              \
        const short* Bp_ = buf_ + row_ * 64 + ((((ic_ << 2) + quad) ^ (row_ & 7)) << 3); \
        BV##0 = *(const bf16x8*)(Bp_);                                                \
        BV##1 = *(const bf16x8*)(Bp_ + 1024);                                         \
        BV##2 = *(const bf16x8*)(Bp_ + 2048);                                         \
        BV##3 = *(const bf16x8*)(Bp_ + 3072);                                         \
    } while (0)

    #define MFMAS(AV, BV) do {                                                        \
        acc[0][0] = __builtin_amdgcn_mfma_f32_16x16x32_bf16(AV##0, BV##0, acc[0][0], 0, 0, 0); \
        acc[0][1] = __builtin_amdgcn_mfma_f32_16x16x32_bf16(AV##0, BV##1, acc[0][1], 0, 0, 0); \
        acc[0][2] = __builtin_amdgcn_mfma_f32_16x16x32_bf16(AV##0, BV##2, acc[0][2], 0, 0, 0); \
        acc[0][3] = __builtin_amdgcn_mfma_f32_16x16x32_bf16(AV##0, BV##3, acc[0][3], 0, 0, 0); \
        acc[1][0] = __builtin_amdgcn_mfma_f32_16x16x32_bf16(AV##1, BV##0, acc[1][0], 0, 0, 0); \
        acc[1][1] = __builtin_amdgcn_mfma_f32_16x16x32_bf16(AV##1, BV##1, acc[1][1], 0, 0, 0); \
        acc[1][2] = __builtin_amdgcn_mfma_f32_16x16x32_bf16(AV##1, BV##2, acc[1][2], 0, 0, 0); \
        acc[1][3] = __builtin_amdgcn_mfma_f32_16x16x32_bf16(AV##1, BV##3, acc[1][3], 0, 0, 0); \
        acc[2][0] = __builtin_amdgcn_mfma_f32_16x16x32_bf16(AV##2, BV##0, acc[2][0], 0, 0, 0); \
        acc[2][1] = __builtin_amdgcn_mfma_f32_16x16x32_bf16(AV##2, BV##1, acc[2][1], 0, 0, 0); \
        acc[2][2] = __builtin_amdgcn_mfma_f32_16x16x32_bf16(AV##2, BV##2, acc[2][2], 0, 0, 0); \
        acc[2][3] = __builtin_amdgcn_mfma_f32_16x16x32_bf16(AV##2, BV##3, acc[2][3], 0, 0, 0); \
        acc[3][0] = __builtin_amdgcn_mfma_f32_16x16x32_bf16(AV##3, BV##0, acc[3][0], 0, 0, 0); \
        acc[3][1] = __builtin_amdgcn_mfma_f32_16x16x32_bf16(AV##3, BV##1, acc[3][1], 0, 0, 0); \
        acc[3][2] = __builtin_amdgcn_mfma_f32_16x16x32_bf16(AV##3, BV##2, acc[3][2], 0, 0, 0); \
        acc[3][3] = __builtin_amdgcn_mfma_f32_16x16x32_bf16(AV##3, BV##3, acc[3][3], 0, 0, 0); \
    } while (0)

    const short* wt_b  = Wt2 + (size_t)b * (9 * 2 * 4096);
    const short* Abase = wt_b + (wm + l15) * 32 + quad * 8;

    STAGE(h0); STAGE(h0 + 1); STAGE(h0 + 2);

    #pragma unroll 1
    for (int h = h0; h < h0 + 8; ++h) {
        __builtin_amdgcn_s_barrier();               // readers of ring slot (h+3)&3 done
        if (h <= h0 + 6) {
            STAGE(h + 3);                           // prefetch next row, stays in flight
            asm volatile("s_waitcnt vmcnt(5)" ::: "memory");   // slab h+2 (and older) done
        } else {
            asm volatile("s_waitcnt vmcnt(0)" ::: "memory");
        }
        __builtin_amdgcn_s_barrier();               // all waves' slab portions visible

        f32x4 acc[4][4];
        #pragma unroll
        for (int mt = 0; mt < 4; mt++)
            #pragma unroll
            for (int nt = 0; nt < 4; nt++)
                acc[mt][nt] = (f32x4){0.f, 0.f, 0.f, 0.f};

        // 1-deep pipelined 18-step K-loop (ping-pong register sets x/y)
        bf16x8 Ax0, Ax1, Ax2, Ax3, Bx0, Bx1, Bx2, Bx3;
        bf16x8 Ay0, Ay1, Ay2, Ay3, By0, By1, By2, By3;
        LOADSTEP(0, Ax, Bx);
        #pragma unroll
        for (int s = 0; s < 18; s++) {
            if ((s & 1) == 0) {
                if (s < 17) LOADSTEP(s + 1, Ay, By);
                MFMAS(Ax, Bx);
            } else {
                if (s < 17) LOADSTEP(s + 1, Ax, Bx);
                MFMAS(Ay, By);
            }
        }

        // epilogue row h: C/D layout col(N)=lane&15, row(M)=quad*4+reg
        #pragma unroll
        for (int mt = 0; mt < 4; mt++) {
            const int o = wm + mt * 16 + quad * 4;
            #pragma unroll
            for (int nt = 0; nt < 4; nt++) {
                const int w = w0 + wn + nt * 16 + l15;
                float* op = out + (((size_t)(b * C_OUT + o) * HW + h) * HW + w);
                #pragma unroll
                for (int r = 0; r < 4; r++) op[(size_t)r * HW * HW] = acc[mt][nt][r];
            }
        }
    }
    #undef STAGE
    #undef LOADSTEP
    #undef MFMAS
}

// ---------------------------------------------------------------------------
// Legacy fallback (verified path) if workspace is too small for xT.
// ---------------------------------------------------------------------------
__global__ __launch_bounds__(256) void pool_kernel(const float* __restrict__ x,
                                                   float* __restrict__ pooled) {
    const int plane = blockIdx.x;
    const float4* p = (const float4*)(x + (size_t)plane * HW * HW);
    float s = 0.f;
    for (int idx = threadIdx.x; idx < (HW * HW) / 4; idx += 256) {
        float4 v = p[idx];
        s += v.x + v.y + v.z + v.w;
    }
    #pragma unroll
    for (int off = 32; off > 0; off >>= 1) s += __shfl_down(s, off, 64);
    __shared__ float ls[4];
    const int lane = threadIdx.x & 63, wv = threadIdx.x >> 6;
    if (lane == 0) ls[wv] = s;
    __syncthreads();
    if (threadIdx.x == 0) {
        float t = ls[0] + ls[1] + ls[2] + ls[3];
        pooled[plane] = t * (1.0f / (HW * HW));
    }
}

__global__ void attn_legacy(const float* __restrict__ pooled,
                            const float* __restrict__ attn_w,
                            const float* __restrict__ attn_b,
                            float* __restrict__ attn) {
    const int t = threadIdx.x;
    const int b = t >> 3, n = t & 7;
    float s = attn_b[n];
    #pragma unroll 8
    for (int c = 0; c < C_IN; c++) s += pooled[b * C_IN + c] * attn_w[n * C_IN + c];
    __shared__ float logits[B_ * NK];
    logits[t] = s;
    __syncthreads();
    float m = -1e30f;
    #pragma unroll
    for (int j = 0; j < NK; j++) m = fmaxf(m, logits[b * NK + j]);
    float denom = 0.f;
    #pragma unroll
    for (int j = 0; j < NK; j++) denom += expf(logits[b * NK + j] - m);
    attn[t] = expf(s - m) / denom;
}

__global__ __launch_bounds__(256) void conv_mfma(const float* __restrict__ x,
                                                 const short* __restrict__ Wt2,
                                                 float* __restrict__ out) {
    const int w0 = blockIdx.x * 128;
    const int h  = blockIdx.y;
    const int b  = blockIdx.z;
    const int t    = threadIdx.x;
    const int lane = t & 63;
    const int wid  = t >> 6;
    const int wm   = (wid & 1) * 64;
    const int wn   = (wid >> 1) * 64;
    const int l15  = lane & 15;
    const int quad = lane >> 4;
    __shared__ short sxs[130 * 72];
    f32x4 acc[4][4];
    #pragma unroll
    for (int mt = 0; mt < 4; mt++)
        #pragma unroll
        for (int nt = 0; nt < 4; nt++)
            acc[mt][nt] = (f32x4){0.f, 0.f, 0.f, 0.f};
    for (int kh = 0; kh < 3; kh++) {
        __syncthreads();
        const int hr = h + kh - 1;
        const bool rv = (hr >= 0) && (hr < HW);
        {
            const int wl = t & 127;
            const int w  = w0 + wl - 1;
            const bool wvalid = rv && (w >= 0) && (w < HW);
            #pragma unroll
            for (int it = 0; it < 16; it++) {
                const int ip = it * 2 + (t >> 7);
                float v0 = 0.f, v1 = 0.f;
                if (wvalid) {
                    const float* px = x + (((size_t)(b * C_IN + 2 * ip) * HW + hr) * HW + w);
                    v0 = px[0];
                    v1 = px[HW * HW];
                }
                ushort2 u;
                u.x = f2bf(v0);
                u.y = f2bf(v1);
                *(ushort2*)&sxs[wl * 72 + 2 * ip] = u;
            }
            if (t < 128) {
                const int i2  = t >> 1;
                const int wl2 = 128 + (t & 1);
                const int w2  = w0 + wl2 - 1;
                unsigned short uv = 0;
                if (rv && w2 < HW)
                    uv = f2bf(x[((size_t)(b * C_IN + i2) * HW + hr) * HW + w2]);
                ((unsigned short*)sxs)[wl2 * 72 + i2] = uv;
            }
        }
        __syncthreads();
        const short* wbase = Wt2 + (size_t)((b * 3 + kh) * 3) * 2 * 4096;
        #pragma unroll
        for (int kw = 0; kw < 3; kw++) {
            #pragma unroll
            for (int ic = 0; ic < 2; ic++) {
                const short* Ap = wbase + (size_t)(kw * 2 + ic) * 4096
                                + (wm + l15) * 32 + quad * 8;
                bf16x8 a0 = *(const bf16x8*)(Ap);
                bf16x8 a1 = *(const bf16x8*)(Ap + 512);
                bf16x8 a2 = *(const bf16x8*)(Ap + 1024);
                bf16x8 a3 = *(const bf16x8*)(Ap + 1536);
                const short* Bp = sxs + (wn + l15 + kw) * 72 + ic * 32 + quad * 8;
                bf16x8 b0 = *(const bf16x8*)(Bp);
                bf16x8 b1 = *(const bf16x8*)(Bp + 16 * 72);
                bf16x8 b2 = *(const bf16x8*)(Bp + 32 * 72);
                bf16x8 b3 = *(const bf16x8*)(Bp + 48 * 72);
                acc[0][0] = __builtin_amdgcn_mfma_f32_16x16x32_bf16(a0, b0, acc[0][0], 0, 0, 0);
                acc[0][1] = __builtin_amdgcn_mfma_f32_16x16x32_bf16(a0, b1, acc[0][1], 0, 0, 0);
                acc[0][2] = __builtin_amdgcn_mfma_f32_16x16x32_bf16(a0, b2, acc[0][2], 0, 0, 0);
                acc[0][3] = __builtin_amdgcn_mfma_f32_16x16x32_bf16(a0, b3, acc[0][3], 0, 0, 0);
                acc[1][0] = __builtin_amdgcn_mfma_f32_16x16x32_bf16(a1, b0, acc[1][0], 0, 0, 0);
                acc[1][1] = __builtin_amdgcn_mfma_f32_16x16x32_bf16(a1, b1, acc[1][1], 0, 0, 0);
                acc[1][2] = __builtin_amdgcn_mfma_f32_16x16x32_bf16(a1, b2, acc[1][2], 0, 0, 0);
                acc[1][3] = __builtin_amdgcn_mfma_f32_16x16x32_bf16(a1, b3, acc[1][3], 0, 0, 0);
                acc[2][0] = __builtin_amdgcn_mfma_f32_16x16x32_bf16(a2, b0, acc[2][0], 0, 0, 0);
                acc[2][1] = __builtin_amdgcn_mfma_f32_16x16x32_bf16(a2, b1, acc[2][1], 0, 0, 0);
                acc[2][2] = __builtin_amdgcn_mfma_f32_16x16x32_bf16(a2, b2, acc[2][2], 0, 0, 0);
                acc[2][3] = __builtin_amdgcn_mfma_f32_16x16x32_bf16(a2, b3, acc[2][3], 0, 0, 0);
                acc[3][0] = __builtin_amdgcn_mfma_f32_16x16x32_bf16(a3, b0, acc[3][0], 0, 0, 0);
                acc[3][1] = __builtin_amdgcn_mfma_f32_16x16x32_bf16(a3, b1, acc[3][1], 0, 0, 0);
                acc[3][2] = __builtin_amdgcn_mfma_f32_16x16x32_bf16(a3, b2, acc[3][2], 0, 0, 0);
                acc[3][3] = __builtin_amdgcn_mfma_f32_16x16x32_bf16(a3, b3, acc[3][3], 0, 0, 0);
            }
        }
    }
    #pragma unroll
    for (int mt = 0; mt < 4; mt++) {
        const int o = wm + mt * 16 + quad * 4;
        #pragma unroll
        for (int nt = 0; nt < 4; nt++) {
            const int w = w0 + wn + nt * 16 + l15;
            float* op = out + (((size_t)(b * C_OUT + o) * HW + h) * HW + w);
            #pragma unroll
            for (int r = 0; r < 4; r++) op[(size_t)r * HW * HW] = acc[mt][nt][r];
        }
    }
}

// ---------------------------------------------------------------------------
extern "C" void kernel_launch(void* const* d_in, const int* in_sizes, int n_in,
                              void* d_out, int out_size, void* d_ws, size_t ws_size,
                              hipStream_t stream) {
    const float* x      = (const float*)d_in[0];   // (8,64,256,256)
    const float* bank   = (const float*)d_in[1];   // (8,128,64,3,3)
    const float* attn_w = (const float*)d_in[2];   // (8,64)
    const float* attn_b = (const float*)d_in[3];   // (8,)
    float* out = (float*)d_out;                    // (8,128,256,256)

    const size_t XT_BYTES  = (size_t)B_ * 258 * XT_PLANE * sizeof(short);        // 68,175,360
    const size_t WT2_BYTES = (size_t)B_ * C_OUT * C_IN * KS * KS * sizeof(short); // 1,179,648
    const size_t PP_BYTES  = (size_t)B_ * 258 * 64 * sizeof(float);               // 528,384
    const size_t NEED = XT_BYTES + WT2_BYTES + PP_BYTES + (size_t)(B_ * NK) * 4 + 256;

    if (ws_size >= NEED) {
        unsigned short* xT  = (unsigned short*)d_ws;
        unsigned short* Wt2 = (unsigned short*)((char*)d_ws + XT_BYTES);
        float* poolpart = (float*)((char*)d_ws + XT_BYTES + WT2_BYTES);
        float* attn     = poolpart + (size_t)B_ * 258 * 64;

        prepass_kernel<<<dim3(258, B_), 256, 0, stream>>>(x, xT, poolpart);
        attn_kernel<<<B_, 256, 0, stream>>>(poolpart, attn_w, attn_b, attn);
        mix_kernel<<<(B_ * C_OUT * C_IN * KS * KS) / 256, 256, 0, stream>>>(bank, attn, Wt2);
        conv_mfma8<<<dim3(2, HW / 8, B_), 256, 0, stream>>>(xT, (const short*)Wt2, out);
    } else {
        // legacy verified path
        unsigned short* Wt2 = (unsigned short*)d_ws;
        float* pooled = (float*)((char*)d_ws + 589824 * sizeof(short));
        float* attn   = pooled + B_ * C_IN;
        pool_kernel<<<B_ * C_IN, 256, 0, stream>>>(x, pooled);
        attn_legacy<<<1, 64, 0, stream>>>(pooled, attn_w, attn_b, attn);
        mix_kernel<<<(B_ * C_OUT * C_IN * KS * KS) / 256, 256, 0, stream>>>(bank, attn, Wt2);
        conv_mfma<<<dim3(2, HW, B_), 256, 0, stream>>>(x, (const short*)Wt2, out);
    }
}

// Round 7
// 482.587 us; speedup vs baseline: 1.1337x; 1.1337x over previous
//
#include <hip/hip_runtime.h>
#include <hip/hip_bf16.h>

#define B_     8
#define C_IN   64
#define C_OUT  128
#define HW     256
#define NK     8
#define KS     3

typedef __attribute__((ext_vector_type(8))) short bf16x8;
typedef __attribute__((ext_vector_type(4))) float f32x4;
typedef __attribute__((ext_vector_type(4))) unsigned int u32x4;

__device__ inline unsigned short f2bf(float f) {
    union { float f; unsigned int u; } a; a.f = f;
    unsigned int u = a.u;
    u += 0x7fffu + ((u >> 16) & 1u);   // round-to-nearest-even
    return (unsigned short)(u >> 16);
}
__device__ inline float bf2f(unsigned short u) {
    union { float f; unsigned int u; } a; a.u = ((unsigned int)u) << 16; return a.f;
}

// xT geometry: [b][hp=258][r=258][c=64] bf16, hp = h+1, r = w+1, zero-padded
// borders. Within each 128-B row the 16-B chunk holding channels 8j..8j+7 is
// stored at slot (j ^ (r & 7)) -> conv's ds_read_b128 is bank-balanced while
// global_load_lds stays a linear copy (swizzle pre-baked in global memory).
#define XT_PLANE  (258 * 64)            /* shorts per (b,hp) plane */
#define SLAB_B    16640                 /* bytes per staged slab: 130 rows x 128 B */

// ---------------------------------------------------------------------------
// Prepass: x fp32 -> swizzled bf16 xT, per-(b,hp) pool partials to scratch.
// grid (258, 8) x 256.
// ---------------------------------------------------------------------------
__global__ __launch_bounds__(256) void prepass_kernel(const float* __restrict__ x,
                                                      unsigned short* __restrict__ xT,
                                                      float* __restrict__ poolpart) {
    const int hp = blockIdx.x;          // 0..257
    const int b  = blockIdx.y;
    const int t  = threadIdx.x;
    unsigned short* plane = xT + ((size_t)b * 258 + hp) * XT_PLANE;

    if (hp == 0 || hp == 257) {         // h-halo planes: all zero
        f32x4 z = {0.f, 0.f, 0.f, 0.f};
        for (int ofs = t * 16; ofs < XT_PLANE * 2; ofs += 256 * 16)
            *(f32x4*)((char*)plane + ofs) = z;
        return;
    }
    const int h = hp - 1;

    __shared__ unsigned short tile[256 * 66];   // [w][c], stride 66 (bank-clean)
    __shared__ float psum[4][64];

    const float* xp = x + ((size_t)b * C_IN * HW + h) * HW + t;   // c=0, w=t
    unsigned int pk[32];
    #pragma unroll
    for (int ci = 0; ci < 32; ci++) {
        float v0 = xp[(size_t)(2 * ci) * (HW * HW)];
        float v1 = xp[(size_t)(2 * ci + 1) * (HW * HW)];
        unsigned int p = (unsigned int)f2bf(v0) | ((unsigned int)f2bf(v1) << 16);
        pk[ci] = p;
        *(unsigned int*)&tile[t * 66 + 2 * ci] = p;
    }

    // swizzled store of row r = t+1
    unsigned short* rowp = plane + (size_t)(t + 1) * 64;
    const int sw = (t + 1) & 7;
    #pragma unroll
    for (int j = 0; j < 8; j++) {
        u32x4 v; v[0] = pk[4*j]; v[1] = pk[4*j+1]; v[2] = pk[4*j+2]; v[3] = pk[4*j+3];
        *(u32x4*)(rowp + (size_t)((j ^ sw) * 8)) = v;
    }
    if (t < 2) {                        // w-halo rows r=0 and r=257: zero
        unsigned short* zr = plane + (size_t)(t ? 257 : 0) * 64;
        f32x4 z = {0.f, 0.f, 0.f, 0.f};
        #pragma unroll
        for (int j = 0; j < 8; j++) *(f32x4*)((char*)zr + j * 16) = z;
    }

    // pool partials: transpose-reduce over w, one row per (b,hp)
    __syncthreads();
    const int c = t & 63, part = t >> 6;
    float s = 0.f;
    #pragma unroll 8
    for (int i = 0; i < 64; i++)
        s += bf2f(tile[(part * 64 + i) * 66 + c]);
    psum[part][c] = s;
    __syncthreads();
    if (t < 64)
        poolpart[((size_t)b * 258 + hp) * 64 + t] =
            (psum[0][t] + psum[1][t]) + (psum[2][t] + psum[3][t]);
}

// ---------------------------------------------------------------------------
// Pool-reduce + logits + softmax.  grid B_ blocks x 256 threads.
// ---------------------------------------------------------------------------
__global__ __launch_bounds__(256) void attn_kernel(const float* __restrict__ poolpart,
                                                   const float* __restrict__ attn_w,
                                                   const float* __restrict__ attn_b,
                                                   float* __restrict__ attn) {
    const int b = blockIdx.x;
    const int t = threadIdx.x;
    const int c = t & 63, part = t >> 6;
    __shared__ float psum[4][64];
    __shared__ float pooled[64];
    __shared__ float logits[NK];

    float s = 0.f;
    const float* pp = poolpart + ((size_t)b * 258) * 64 + c;
    for (int hp = part * 64 + 1; hp <= part * 64 + 64; hp++)
        s += pp[(size_t)hp * 64];
    psum[part][c] = s;
    __syncthreads();
    if (t < 64)
        pooled[t] = ((psum[0][t] + psum[1][t]) + (psum[2][t] + psum[3][t]))
                    * (1.0f / (HW * HW));
    __syncthreads();
    if (t < NK) {
        float l = attn_b[t];
        #pragma unroll 8
        for (int cc = 0; cc < C_IN; cc++) l += pooled[cc] * attn_w[t * C_IN + cc];
        logits[t] = l;
    }
    __syncthreads();
    if (t < NK) {
        float m = -1e30f;
        #pragma unroll
        for (int j = 0; j < NK; j++) m = fmaxf(m, logits[j]);
        float denom = 0.f;
        #pragma unroll
        for (int j = 0; j < NK; j++) denom += expf(logits[j] - m);
        attn[b * NK + t] = expf(logits[t] - m) / denom;
    }
}

// ---------------------------------------------------------------------------
// mixed weights -> bf16, pre-swizzled into MFMA A-fragment order:
//   Wt2[b][kh][kw][ic][o][di]  (ic = i>>5, di = i&31)
// ---------------------------------------------------------------------------
__global__ __launch_bounds__(256) void mix_kernel(const float* __restrict__ bank,
                                                  const float* __restrict__ attn,
                                                  unsigned short* __restrict__ Wt2) {
    const int PER_B = C_OUT * C_IN * KS * KS;   // 73728
    int idx = blockIdx.x * 256 + threadIdx.x;
    int b = idx / PER_B;
    int r = idx % PER_B;
    float s = 0.f;
    #pragma unroll
    for (int n = 0; n < NK; n++) s += attn[b * NK + n] * bank[(size_t)n * PER_B + r];
    int kw = r % 3;
    int t1 = r / 3;
    int kh = t1 % 3;
    int t2 = t1 / 3;
    int i = t2 & 63;
    int o = t2 >> 6;
    size_t off = (((size_t)((b * 3 + kh) * 3 + kw) * 2 + (i >> 5)) * 128 + o) * 32 + (i & 31);
    Wt2[off] = f2bf(s);
}

// ---------------------------------------------------------------------------
// Conv v9: EXACT round-1 conv2 (best measured, ~127 us) with ONE change:
// the steady-state wait is vmcnt(63) instead of vmcnt(5), so the per-row
// drain no longer waits for the previous row's 64 output stores.
// Correctness bound: at the wait, in-flight <= 5 stage(h+2,oldest) + 64
// stores + 5 stage(h+3) = 74; oldest-5-complete requires outstanding <= 69,
// and vmcnt(63) <= 69. Prologue row keeps vmcnt(5) (15 preload entries must
// drain). Tail rows: same 74-bound argument, vmcnt(63) safe.
// grid = (2 w-halves, 32 h-tiles, 8 b), block = 256 (4 waves, 2x2 of 64x64).
// ---------------------------------------------------------------------------
__global__ __launch_bounds__(256, 2) void conv_mfma9(const unsigned short* __restrict__ xT,
                                                     const short* __restrict__ Wt2,
                                                     float* __restrict__ out) {
    const int w0 = blockIdx.x * 128;   // 0 or 128
    const int h0 = blockIdx.y * 8;
    const int b  = blockIdx.z;

    const int t    = threadIdx.x;
    const int lane = t & 63;
    const int wid  = t >> 6;
    const int wm   = (wid & 1) * 64;   // wave M offset
    const int wn   = (wid >> 1) * 64;  // wave N offset
    const int l15  = lane & 15;
    const int quad = lane >> 4;

    __shared__ short sxs[4 * 8320];     // 4 ring slabs x 16640 B

    #define STAGE(HP) do {                                                            \
        const char* _src = (const char*)(xT + (((size_t)b * 258 + (size_t)(HP)) * 258 \
                                               + (size_t)w0) * 64);                   \
        char* _dst = (char*)sxs + (((HP) & 3) * SLAB_B);                              \
        const int _wo = wid * 4096;                                                   \
        __builtin_amdgcn_global_load_lds((const __attribute__((address_space(1))) void*)(_src + _wo +        lane * 16), (__attribute__((address_space(3))) void*)(_dst + _wo),        16, 0, 0); \
        __builtin_amdgcn_global_load_lds((const __attribute__((address_space(1))) void*)(_src + _wo + 1024 + lane * 16), (__attribute__((address_space(3))) void*)(_dst + _wo + 1024), 16, 0, 0); \
        __builtin_amdgcn_global_load_lds((const __attribute__((address_space(1))) void*)(_src + _wo + 2048 + lane * 16), (__attribute__((address_space(3))) void*)(_dst + _wo + 2048), 16, 0, 0); \
        __builtin_amdgcn_global_load_lds((const __attribute__((address_space(1))) void*)(_src + _wo + 3072 + lane * 16), (__attribute__((address_space(3))) void*)(_dst + _wo + 3072), 16, 0, 0); \
        __builtin_amdgcn_global_load_lds((const __attribute__((address_space(1))) void*)(_src + 16384 + lane * 4),       (__attribute__((address_space(3))) void*)(_dst + 16384),        4, 0, 0); \
    } while (0)

    f32x4 acc[4][4];

    STAGE(h0); STAGE(h0 + 1); STAGE(h0 + 2);

    #pragma unroll 1
    for (int h = h0; h < h0 + 8; ++h) {
        __builtin_amdgcn_s_barrier();               // readers of ring slot (h+3)&3 done
        if (h == h0) {
            STAGE(h + 3);
            asm volatile("s_waitcnt vmcnt(5)" ::: "memory");    // drain 3-slab preload
        } else if (h <= h0 + 6) {
            STAGE(h + 3);
            asm volatile("s_waitcnt vmcnt(63)" ::: "memory");   // slab h+2 done; stores fly
        } else {
            asm volatile("s_waitcnt vmcnt(63)" ::: "memory");   // slab h+2 done; stores fly
        }
        __builtin_amdgcn_s_barrier();               // all waves' slab portions visible

        #pragma unroll
        for (int mt = 0; mt < 4; mt++)
            #pragma unroll
            for (int nt = 0; nt < 4; nt++)
                acc[mt][nt] = (f32x4){0.f, 0.f, 0.f, 0.f};

        const short* wbase = Wt2 + (size_t)b * (9 * 2 * 4096) + (size_t)(3 * 2 * 4096) * 0;
        #pragma unroll
        for (int kh = 0; kh < 3; kh++) {
            const short* buf = sxs + ((h + kh) & 3) * 8320;
            const short* wb2 = Wt2 + (size_t)((b * 3 + kh) * 3) * 2 * 4096;
            #pragma unroll
            for (int kw = 0; kw < 3; kw++) {
                const int row = wn + l15 + kw;      // LDS row == xT row mod 8 (w0%8==0)
                const int rx  = row & 7;
                #pragma unroll
                for (int ic = 0; ic < 2; ic++) {
                    const short* Ap = wb2 + (kw * 2 + ic) * 4096 + (wm + l15) * 32 + quad * 8;
                    bf16x8 a0 = *(const bf16x8*)(Ap);
                    bf16x8 a1 = *(const bf16x8*)(Ap + 512);
                    bf16x8 a2 = *(const bf16x8*)(Ap + 1024);
                    bf16x8 a3 = *(const bf16x8*)(Ap + 1536);
                    // rows +16/+32/+48 share (row&7): one swizzled base serves all 4
                    const short* Bp = buf + row * 64 + (((ic << 2) + quad) ^ rx) * 8;
                    bf16x8 b0 = *(const bf16x8*)(Bp);
                    bf16x8 b1 = *(const bf16x8*)(Bp + 1024);
                    bf16x8 b2 = *(const bf16x8*)(Bp + 2048);
                    bf16x8 b3 = *(const bf16x8*)(Bp + 3072);
                    acc[0][0] = __builtin_amdgcn_mfma_f32_16x16x32_bf16(a0, b0, acc[0][0], 0, 0, 0);
                    acc[0][1] = __builtin_amdgcn_mfma_f32_16x16x32_bf16(a0, b1, acc[0][1], 0, 0, 0);
                    acc[0][2] = __builtin_amdgcn_mfma_f32_16x16x32_bf16(a0, b2, acc[0][2], 0, 0, 0);
                    acc[0][3] = __builtin_amdgcn_mfma_f32_16x16x32_bf16(a0, b3, acc[0][3], 0, 0, 0);
                    acc[1][0] = __builtin_amdgcn_mfma_f32_16x16x32_bf16(a1, b0, acc[1][0], 0, 0, 0);
                    acc[1][1] = __builtin_amdgcn_mfma_f32_16x16x32_bf16(a1, b1, acc[1][1], 0, 0, 0);
                    acc[1][2] = __builtin_amdgcn_mfma_f32_16x16x32_bf16(a1, b2, acc[1][2], 0, 0, 0);
                    acc[1][3] = __builtin_amdgcn_mfma_f32_16x16x32_bf16(a1, b3, acc[1][3], 0, 0, 0);
                    acc[2][0] = __builtin_amdgcn_mfma_f32_16x16x32_bf16(a2, b0, acc[2][0], 0, 0, 0);
                    acc[2][1] = __builtin_amdgcn_mfma_f32_16x16x32_bf16(a2, b1, acc[2][1], 0, 0, 0);
                    acc[2][2] = __builtin_amdgcn_mfma_f32_16x16x32_bf16(a2, b2, acc[2][2], 0, 0, 0);
                    acc[2][3] = __builtin_amdgcn_mfma_f32_16x16x32_bf16(a2, b3, acc[2][3], 0, 0, 0);
                    acc[3][0] = __builtin_amdgcn_mfma_f32_16x16x32_bf16(a3, b0, acc[3][0], 0, 0, 0);
                    acc[3][1] = __builtin_amdgcn_mfma_f32_16x16x32_bf16(a3, b1, acc[3][1], 0, 0, 0);
                    acc[3][2] = __builtin_amdgcn_mfma_f32_16x16x32_bf16(a3, b2, acc[3][2], 0, 0, 0);
                    acc[3][3] = __builtin_amdgcn_mfma_f32_16x16x32_bf16(a3, b3, acc[3][3], 0, 0, 0);
                }
            }
        }
        (void)wbase;

        // epilogue row h: C/D layout col(N)=lane&15, row(M)=quad*4+reg
        #pragma unroll
        for (int mt = 0; mt < 4; mt++) {
            const int o = wm + mt * 16 + quad * 4;
            #pragma unroll
            for (int nt = 0; nt < 4; nt++) {
                const int w = w0 + wn + nt * 16 + l15;
                float* op = out + (((size_t)(b * C_OUT + o) * HW + h) * HW + w);
                #pragma unroll
                for (int r = 0; r < 4; r++) op[(size_t)r * HW * HW] = acc[mt][nt][r];
            }
        }
    }
    #undef STAGE
}

// ---------------------------------------------------------------------------
// Legacy fallback (verified path) if workspace is too small for xT.
// ---------------------------------------------------------------------------
__global__ __launch_bounds__(256) void pool_kernel(const float* __restrict__ x,
                                                   float* __restrict__ pooled) {
    const int plane = blockIdx.x;
    const float4* p = (const float4*)(x + (size_t)plane * HW * HW);
    float s = 0.f;
    for (int idx = threadIdx.x; idx < (HW * HW) / 4; idx += 256) {
        float4 v = p[idx];
        s += v.x + v.y + v.z + v.w;
    }
    #pragma unroll
    for (int off = 32; off > 0; off >>= 1) s += __shfl_down(s, off, 64);
    __shared__ float ls[4];
    const int lane = threadIdx.x & 63, wv = threadIdx.x >> 6;
    if (lane == 0) ls[wv] = s;
    __syncthreads();
    if (threadIdx.x == 0) {
        float t = ls[0] + ls[1] + ls[2] + ls[3];
        pooled[plane] = t * (1.0f / (HW * HW));
    }
}

__global__ void attn_legacy(const float* __restrict__ pooled,
                            const float* __restrict__ attn_w,
                            const float* __restrict__ attn_b,
                            float* __restrict__ attn) {
    const int t = threadIdx.x;
    const int b = t >> 3, n = t & 7;
    float s = attn_b[n];
    #pragma unroll 8
    for (int c = 0; c < C_IN; c++) s += pooled[b * C_IN + c] * attn_w[n * C_IN + c];
    __shared__ float logits[B_ * NK];
    logits[t] = s;
    __syncthreads();
    float m = -1e30f;
    #pragma unroll
    for (int j = 0; j < NK; j++) m = fmaxf(m, logits[b * NK + j]);
    float denom = 0.f;
    #pragma unroll
    for (int j = 0; j < NK; j++) denom += expf(logits[b * NK + j] - m);
    attn[t] = expf(s - m) / denom;
}

__global__ __launch_bounds__(256) void conv_mfma(const float* __restrict__ x,
                                                 const short* __restrict__ Wt2,
                                                 float* __restrict__ out) {
    const int w0 = blockIdx.x * 128;
    const int h  = blockIdx.y;
    const int b  = blockIdx.z;
    const int t    = threadIdx.x;
    const int lane = t & 63;
    const int wid  = t >> 6;
    const int wm   = (wid & 1) * 64;
    const int wn   = (wid >> 1) * 64;
    const int l15  = lane & 15;
    const int quad = lane >> 4;
    __shared__ short sxs[130 * 72];
    f32x4 acc[4][4];
    #pragma unroll
    for (int mt = 0; mt < 4; mt++)
        #pragma unroll
        for (int nt = 0; nt < 4; nt++)
            acc[mt][nt] = (f32x4){0.f, 0.f, 0.f, 0.f};
    for (int kh = 0; kh < 3; kh++) {
        __syncthreads();
        const int hr = h + kh - 1;
        const bool rv = (hr >= 0) && (hr < HW);
        {
            const int wl = t & 127;
            const int w  = w0 + wl - 1;
            const bool wvalid = rv && (w >= 0) && (w < HW);
            #pragma unroll
            for (int it = 0; it < 16; it++) {
                const int ip = it * 2 + (t >> 7);
                float v0 = 0.f, v1 = 0.f;
                if (wvalid) {
                    const float* px = x + (((size_t)(b * C_IN + 2 * ip) * HW + hr) * HW + w);
                    v0 = px[0];
                    v1 = px[HW * HW];
                }
                ushort2 u;
                u.x = f2bf(v0);
                u.y = f2bf(v1);
                *(ushort2*)&sxs[wl * 72 + 2 * ip] = u;
            }
            if (t < 128) {
                const int i2  = t >> 1;
                const int wl2 = 128 + (t & 1);
                const int w2  = w0 + wl2 - 1;
                unsigned short uv = 0;
                if (rv && w2 < HW)
                    uv = f2bf(x[((size_t)(b * C_IN + i2) * HW + hr) * HW + w2]);
                ((unsigned short*)sxs)[wl2 * 72 + i2] = uv;
            }
        }
        __syncthreads();
        const short* wbase = Wt2 + (size_t)((b * 3 + kh) * 3) * 2 * 4096;
        #pragma unroll
        for (int kw = 0; kw < 3; kw++) {
            #pragma unroll
            for (int ic = 0; ic < 2; ic++) {
                const short* Ap = wbase + (size_t)(kw * 2 + ic) * 4096
                                + (wm + l15) * 32 + quad * 8;
                bf16x8 a0 = *(const bf16x8*)(Ap);
                bf16x8 a1 = *(const bf16x8*)(Ap + 512);
                bf16x8 a2 = *(const bf16x8*)(Ap + 1024);
                bf16x8 a3 = *(const bf16x8*)(Ap + 1536);
                const short* Bp = sxs + (wn + l15 + kw) * 72 + ic * 32 + quad * 8;
                bf16x8 b0 = *(const bf16x8*)(Bp);
                bf16x8 b1 = *(const bf16x8*)(Bp + 16 * 72);
                bf16x8 b2 = *(const bf16x8*)(Bp + 32 * 72);
                bf16x8 b3 = *(const bf16x8*)(Bp + 48 * 72);
                acc[0][0] = __builtin_amdgcn_mfma_f32_16x16x32_bf16(a0, b0, acc[0][0], 0, 0, 0);
                acc[0][1] = __builtin_amdgcn_mfma_f32_16x16x32_bf16(a0, b1, acc[0][1], 0, 0, 0);
                acc[0][2] = __builtin_amdgcn_mfma_f32_16x16x32_bf16(a0, b2, acc[0][2], 0, 0, 0);
                acc[0][3] = __builtin_amdgcn_mfma_f32_16x16x32_bf16(a0, b3, acc[0][3], 0, 0, 0);
                acc[1][0] = __builtin_amdgcn_mfma_f32_16x16x32_bf16(a1, b0, acc[1][0], 0, 0, 0);
                acc[1][1] = __builtin_amdgcn_mfma_f32_16x16x32_bf16(a1, b1, acc[1][1], 0, 0, 0);
                acc[1][2] = __builtin_amdgcn_mfma_f32_16x16x32_bf16(a1, b2, acc[1][2], 0, 0, 0);
                acc[1][3] = __builtin_amdgcn_mfma_f32_16x16x32_bf16(a1, b3, acc[1][3], 0, 0, 0);
                acc[2][0] = __builtin_amdgcn_mfma_f32_16x16x32_bf16(a2, b0, acc[2][0], 0, 0, 0);
                acc[2][1] = __builtin_amdgcn_mfma_f32_16x16x32_bf16(a2, b1, acc[2][1], 0, 0, 0);
                acc[2][2] = __builtin_amdgcn_mfma_f32_16x16x32_bf16(a2, b2, acc[2][2], 0, 0, 0);
                acc[2][3] = __builtin_amdgcn_mfma_f32_16x16x32_bf16(a2, b3, acc[2][3], 0, 0, 0);
                acc[3][0] = __builtin_amdgcn_mfma_f32_16x16x32_bf16(a3, b0, acc[3][0], 0, 0, 0);
                acc[3][1] = __builtin_amdgcn_mfma_f32_16x16x32_bf16(a3, b1, acc[3][1], 0, 0, 0);
                acc[3][2] = __builtin_amdgcn_mfma_f32_16x16x32_bf16(a3, b2, acc[3][2], 0, 0, 0);
                acc[3][3] = __builtin_amdgcn_mfma_f32_16x16x32_bf16(a3, b3, acc[3][3], 0, 0, 0);
            }
        }
    }
    #pragma unroll
    for (int mt = 0; mt < 4; mt++) {
        const int o = wm + mt * 16 + quad * 4;
        #pragma unroll
        for (int nt = 0; nt < 4; nt++) {
            const int w = w0 + wn + nt * 16 + l15;
            float* op = out + (((size_t)(b * C_OUT + o) * HW + h) * HW + w);
            #pragma unroll
            for (int r = 0; r < 4; r++) op[(size_t)r * HW * HW] = acc[mt][nt][r];
        }
    }
}

// ---------------------------------------------------------------------------
extern "C" void kernel_launch(void* const* d_in, const int* in_sizes, int n_in,
                              void* d_out, int out_size, void* d_ws, size_t ws_size,
                              hipStream_t stream) {
    const float* x      = (const float*)d_in[0];   // (8,64,256,256)
    const float* bank   = (const float*)d_in[1];   // (8,128,64,3,3)
    const float* attn_w = (const float*)d_in[2];   // (8,64)
    const float* attn_b = (const float*)d_in[3];   // (8,)
    float* out = (float*)d_out;                    // (8,128,256,256)

    const size_t XT_BYTES  = (size_t)B_ * 258 * XT_PLANE * sizeof(short);        // 68,175,360
    const size_t WT2_BYTES = (size_t)B_ * C_OUT * C_IN * KS * KS * sizeof(short); // 1,179,648
    const size_t PP_BYTES  = (size_t)B_ * 258 * 64 * sizeof(float);               // 528,384
    const size_t NEED = XT_BYTES + WT2_BYTES + PP_BYTES + (size_t)(B_ * NK) * 4 + 256;

    if (ws_size >= NEED) {
        unsigned short* xT  = (unsigned short*)d_ws;
        unsigned short* Wt2 = (unsigned short*)((char*)d_ws + XT_BYTES);
        float* poolpart = (float*)((char*)d_ws + XT_BYTES + WT2_BYTES);
        float* attn     = poolpart + (size_t)B_ * 258 * 64;

        prepass_kernel<<<dim3(258, B_), 256, 0, stream>>>(x, xT, poolpart);
        attn_kernel<<<B_, 256, 0, stream>>>(poolpart, attn_w, attn_b, attn);
        mix_kernel<<<(B_ * C_OUT * C_IN * KS * KS) / 256, 256, 0, stream>>>(bank, attn, Wt2);
        conv_mfma9<<<dim3(2, HW / 8, B_), 256, 0, stream>>>(xT, (const short*)Wt2, out);
    } else {
        // legacy verified path
        unsigned short* Wt2 = (unsigned short*)d_ws;
        float* pooled = (float*)((char*)d_ws + 589824 * sizeof(short));
        float* attn   = pooled + B_ * C_IN;
        pool_kernel<<<B_ * C_IN, 256, 0, stream>>>(x, pooled);
        attn_legacy<<<1, 64, 0, stream>>>(pooled, attn_w, attn_b, attn);
        mix_kernel<<<(B_ * C_OUT * C_IN * KS * KS) / 256, 256, 0, stream>>>(bank, attn, Wt2);
        conv_mfma<<<dim3(2, HW, B_), 256, 0, stream>>>(x, (const short*)Wt2, out);
    }
}

// Round 8
// 476.249 us; speedup vs baseline: 1.1488x; 1.0133x over previous
//
#include <hip/hip_runtime.h>
#include <hip/hip_bf16.h>

#define B_     8
#define C_IN   64
#define C_OUT  128
#define HW     256
#define NK     8
#define KS     3

typedef __attribute__((ext_vector_type(8))) short bf16x8;
typedef __attribute__((ext_vector_type(4))) float f32x4;
typedef __attribute__((ext_vector_type(4))) unsigned int u32x4;

__device__ inline unsigned short f2bf(float f) {
    union { float f; unsigned int u; } a; a.f = f;
    unsigned int u = a.u;
    u += 0x7fffu + ((u >> 16) & 1u);   // round-to-nearest-even
    return (unsigned short)(u >> 16);
}
__device__ inline float bf2f(unsigned short u) {
    union { float f; unsigned int u; } a; a.u = ((unsigned int)u) << 16; return a.f;
}
// packed RNE f32x2 -> bf16x2 via hardware v_cvt_pk_bf16_f32 (bit-identical
// to the manual f2bf pair, 1 instr instead of ~8)
__device__ inline unsigned int f2bf_pk(float lo, float hi) {
    float2 f2; f2.x = lo; f2.y = hi;
    __hip_bfloat162 bb = __float22bfloat162_rn(f2);
    unsigned int p;
    __builtin_memcpy(&p, &bb, 4);
    return p;
}

// xT geometry: [b][hp=258][r=258][c=64] bf16, hp = h+1, r = w+1, zero-padded
// borders. Within each 128-B row the 16-B chunk holding channels 8j..8j+7 is
// stored at slot (j ^ (r & 7)) -> conv's ds_read_b128 is bank-balanced while
// global_load_lds stays a linear copy (swizzle pre-baked in global memory).
#define XT_PLANE  (258 * 64)            /* shorts per (b,hp) plane */
#define SLAB_B    16640                 /* bytes per staged slab: 130 rows x 128 B */

// ---------------------------------------------------------------------------
// Prepass: x fp32 -> swizzled bf16 xT, per-(b,hp) pool partials to scratch.
// grid (258, 8) x 256.  v2: packed hardware cvt (v_cvt_pk_bf16_f32).
// ---------------------------------------------------------------------------
__global__ __launch_bounds__(256) void prepass_kernel(const float* __restrict__ x,
                                                      unsigned short* __restrict__ xT,
                                                      float* __restrict__ poolpart) {
    const int hp = blockIdx.x;          // 0..257
    const int b  = blockIdx.y;
    const int t  = threadIdx.x;
    unsigned short* plane = xT + ((size_t)b * 258 + hp) * XT_PLANE;

    if (hp == 0 || hp == 257) {         // h-halo planes: all zero
        f32x4 z = {0.f, 0.f, 0.f, 0.f};
        for (int ofs = t * 16; ofs < XT_PLANE * 2; ofs += 256 * 16)
            *(f32x4*)((char*)plane + ofs) = z;
        return;
    }
    const int h = hp - 1;

    __shared__ unsigned short tile[256 * 66];   // [w][c], stride 66 (bank-clean)
    __shared__ float psum[4][64];

    const float* xp = x + ((size_t)b * C_IN * HW + h) * HW + t;   // c=0, w=t
    unsigned int pk[32];
    #pragma unroll
    for (int ci = 0; ci < 32; ci++) {
        float v0 = xp[(size_t)(2 * ci) * (HW * HW)];
        float v1 = xp[(size_t)(2 * ci + 1) * (HW * HW)];
        unsigned int p = f2bf_pk(v0, v1);
        pk[ci] = p;
        *(unsigned int*)&tile[t * 66 + 2 * ci] = p;
    }

    // swizzled store of row r = t+1
    unsigned short* rowp = plane + (size_t)(t + 1) * 64;
    const int sw = (t + 1) & 7;
    #pragma unroll
    for (int j = 0; j < 8; j++) {
        u32x4 v; v[0] = pk[4*j]; v[1] = pk[4*j+1]; v[2] = pk[4*j+2]; v[3] = pk[4*j+3];
        *(u32x4*)(rowp + (size_t)((j ^ sw) * 8)) = v;
    }
    if (t < 2) {                        // w-halo rows r=0 and r=257: zero
        unsigned short* zr = plane + (size_t)(t ? 257 : 0) * 64;
        f32x4 z = {0.f, 0.f, 0.f, 0.f};
        #pragma unroll
        for (int j = 0; j < 8; j++) *(f32x4*)((char*)zr + j * 16) = z;
    }

    // pool partials: transpose-reduce over w, one row per (b,hp)
    __syncthreads();
    const int c = t & 63, part = t >> 6;
    float s = 0.f;
    #pragma unroll 8
    for (int i = 0; i < 64; i++)
        s += bf2f(tile[(part * 64 + i) * 66 + c]);
    psum[part][c] = s;
    __syncthreads();
    if (t < 64)
        poolpart[((size_t)b * 258 + hp) * 64 + t] =
            (psum[0][t] + psum[1][t]) + (psum[2][t] + psum[3][t]);
}

// ---------------------------------------------------------------------------
// Pool-reduce + logits + softmax.  grid B_ blocks x 256 threads.
// ---------------------------------------------------------------------------
__global__ __launch_bounds__(256) void attn_kernel(const float* __restrict__ poolpart,
                                                   const float* __restrict__ attn_w,
                                                   const float* __restrict__ attn_b,
                                                   float* __restrict__ attn) {
    const int b = blockIdx.x;
    const int t = threadIdx.x;
    const int c = t & 63, part = t >> 6;
    __shared__ float psum[4][64];
    __shared__ float pooled[64];
    __shared__ float logits[NK];

    float s = 0.f;
    const float* pp = poolpart + ((size_t)b * 258) * 64 + c;
    for (int hp = part * 64 + 1; hp <= part * 64 + 64; hp++)
        s += pp[(size_t)hp * 64];
    psum[part][c] = s;
    __syncthreads();
    if (t < 64)
        pooled[t] = ((psum[0][t] + psum[1][t]) + (psum[2][t] + psum[3][t]))
                    * (1.0f / (HW * HW));
    __syncthreads();
    if (t < NK) {
        float l = attn_b[t];
        #pragma unroll 8
        for (int cc = 0; cc < C_IN; cc++) l += pooled[cc] * attn_w[t * C_IN + cc];
        logits[t] = l;
    }
    __syncthreads();
    if (t < NK) {
        float m = -1e30f;
        #pragma unroll
        for (int j = 0; j < NK; j++) m = fmaxf(m, logits[j]);
        float denom = 0.f;
        #pragma unroll
        for (int j = 0; j < NK; j++) denom += expf(logits[j] - m);
        attn[b * NK + t] = expf(logits[t] - m) / denom;
    }
}

// ---------------------------------------------------------------------------
// mixed weights -> bf16, pre-swizzled into MFMA A-fragment order:
//   Wt2[b][kh][kw][ic][o][di]  (ic = i>>5, di = i&31)
// ---------------------------------------------------------------------------
__global__ __launch_bounds__(256) void mix_kernel(const float* __restrict__ bank,
                                                  const float* __restrict__ attn,
                                                  unsigned short* __restrict__ Wt2) {
    const int PER_B = C_OUT * C_IN * KS * KS;   // 73728
    int idx = blockIdx.x * 256 + threadIdx.x;
    int b = idx / PER_B;
    int r = idx % PER_B;
    float s = 0.f;
    #pragma unroll
    for (int n = 0; n < NK; n++) s += attn[b * NK + n] * bank[(size_t)n * PER_B + r];
    int kw = r % 3;
    int t1 = r / 3;
    int kh = t1 % 3;
    int t2 = t1 / 3;
    int i = t2 & 63;
    int o = t2 >> 6;
    size_t off = (((size_t)((b * 3 + kh) * 3 + kw) * 2 + (i >> 5)) * 128 + o) * 32 + (i & 31);
    Wt2[off] = f2bf(s);
}

// ---------------------------------------------------------------------------
// Conv v2 (round-1 best-measured configuration, byte-exact): implicit GEMM,
// 8 output rows / block, 4-slab LDS ring fed by global_load_lds, vmcnt(5),
// raw barriers, swizzled ds_read_b128.
// grid (2 w-halves, 32 h-tiles, 8 b), block = 256 (4 waves, 2x2 of 64x64).
// ---------------------------------------------------------------------------
__global__ __launch_bounds__(256, 2) void conv_mfma2(const unsigned short* __restrict__ xT,
                                                     const short* __restrict__ Wt2,
                                                     float* __restrict__ out) {
    const int w0 = blockIdx.x * 128;
    const int h0 = blockIdx.y * 8;
    const int b  = blockIdx.z;
    const int t    = threadIdx.x;
    const int lane = t & 63;
    const int wid  = t >> 6;
    const int wm   = (wid & 1) * 64;   // wave M offset
    const int wn   = (wid >> 1) * 64;  // wave N offset
    const int l15  = lane & 15;
    const int quad = lane >> 4;

    __shared__ short sxs[4 * 8320];     // 4 ring slabs x 16640 B

    #define STAGE(HP) do {                                                            \
        const char* _src = (const char*)(xT + (((size_t)b * 258 + (size_t)(HP)) * 258 \
                                               + (size_t)w0) * 64);                   \
        char* _dst = (char*)sxs + (((HP) & 3) * SLAB_B);                              \
        const int _wo = wid * 4096;                                                   \
        __builtin_amdgcn_global_load_lds((const __attribute__((address_space(1))) void*)(_src + _wo +        lane * 16), (__attribute__((address_space(3))) void*)(_dst + _wo),        16, 0, 0); \
        __builtin_amdgcn_global_load_lds((const __attribute__((address_space(1))) void*)(_src + _wo + 1024 + lane * 16), (__attribute__((address_space(3))) void*)(_dst + _wo + 1024), 16, 0, 0); \
        __builtin_amdgcn_global_load_lds((const __attribute__((address_space(1))) void*)(_src + _wo + 2048 + lane * 16), (__attribute__((address_space(3))) void*)(_dst + _wo + 2048), 16, 0, 0); \
        __builtin_amdgcn_global_load_lds((const __attribute__((address_space(1))) void*)(_src + _wo + 3072 + lane * 16), (__attribute__((address_space(3))) void*)(_dst + _wo + 3072), 16, 0, 0); \
        __builtin_amdgcn_global_load_lds((const __attribute__((address_space(1))) void*)(_src + 16384 + lane * 4),       (__attribute__((address_space(3))) void*)(_dst + 16384),        4, 0, 0); \
    } while (0)

    const short* wt_b = Wt2 + (size_t)b * (9 * 2 * 4096);

    STAGE(h0); STAGE(h0 + 1); STAGE(h0 + 2);

    #pragma unroll 1
    for (int h = h0; h < h0 + 8; ++h) {
        __builtin_amdgcn_s_barrier();               // all readers of slab (h+3)&3 done
        if (h <= h0 + 6) {
            STAGE(h + 3);                           // prefetch next row, stays in flight
            asm volatile("s_waitcnt vmcnt(5)" ::: "memory");   // slab h+2 (and older) done
        } else {
            asm volatile("s_waitcnt vmcnt(0)" ::: "memory");
        }
        __builtin_amdgcn_s_barrier();               // all waves' slab portions visible

        f32x4 acc[4][4];
        #pragma unroll
        for (int mt = 0; mt < 4; mt++)
            #pragma unroll
            for (int nt = 0; nt < 4; nt++)
                acc[mt][nt] = (f32x4){0.f, 0.f, 0.f, 0.f};

        #pragma unroll
        for (int kh = 0; kh < 3; kh++) {
            const short* buf = sxs + ((h + kh) & 3) * 8320;
            const short* wbase = wt_b + kh * (3 * 2 * 4096);
            #pragma unroll
            for (int kw = 0; kw < 3; kw++) {
                const int row = wn + l15 + kw;      // LDS row == xT row mod 8 (w0%8==0)
                const int rx  = row & 7;
                #pragma unroll
                for (int ic = 0; ic < 2; ic++) {
                    const short* Ap = wbase + (kw * 2 + ic) * 4096 + (wm + l15) * 32 + quad * 8;
                    bf16x8 a0 = *(const bf16x8*)(Ap);
                    bf16x8 a1 = *(const bf16x8*)(Ap + 512);
                    bf16x8 a2 = *(const bf16x8*)(Ap + 1024);
                    bf16x8 a3 = *(const bf16x8*)(Ap + 1536);
                    // rows +16/+32/+48 share (row&7): one swizzled base serves all 4
                    const short* Bp = buf + row * 64 + (((ic << 2) + quad) ^ rx) * 8;
                    bf16x8 b0 = *(const bf16x8*)(Bp);
                    bf16x8 b1 = *(const bf16x8*)(Bp + 1024);
                    bf16x8 b2 = *(const bf16x8*)(Bp + 2048);
                    bf16x8 b3 = *(const bf16x8*)(Bp + 3072);
                    acc[0][0] = __builtin_amdgcn_mfma_f32_16x16x32_bf16(a0, b0, acc[0][0], 0, 0, 0);
                    acc[0][1] = __builtin_amdgcn_mfma_f32_16x16x32_bf16(a0, b1, acc[0][1], 0, 0, 0);
                    acc[0][2] = __builtin_amdgcn_mfma_f32_16x16x32_bf16(a0, b2, acc[0][2], 0, 0, 0);
                    acc[0][3] = __builtin_amdgcn_mfma_f32_16x16x32_bf16(a0, b3, acc[0][3], 0, 0, 0);
                    acc[1][0] = __builtin_amdgcn_mfma_f32_16x16x32_bf16(a1, b0, acc[1][0], 0, 0, 0);
                    acc[1][1] = __builtin_amdgcn_mfma_f32_16x16x32_bf16(a1, b1, acc[1][1], 0, 0, 0);
                    acc[1][2] = __builtin_amdgcn_mfma_f32_16x16x32_bf16(a1, b2, acc[1][2], 0, 0, 0);
                    acc[1][3] = __builtin_amdgcn_mfma_f32_16x16x32_bf16(a1, b3, acc[1][3], 0, 0, 0);
                    acc[2][0] = __builtin_amdgcn_mfma_f32_16x16x32_bf16(a2, b0, acc[2][0], 0, 0, 0);
                    acc[2][1] = __builtin_amdgcn_mfma_f32_16x16x32_bf16(a2, b1, acc[2][1], 0, 0, 0);
                    acc[2][2] = __builtin_amdgcn_mfma_f32_16x16x32_bf16(a2, b2, acc[2][2], 0, 0, 0);
                    acc[2][3] = __builtin_amdgcn_mfma_f32_16x16x32_bf16(a2, b3, acc[2][3], 0, 0, 0);
                    acc[3][0] = __builtin_amdgcn_mfma_f32_16x16x32_bf16(a3, b0, acc[3][0], 0, 0, 0);
                    acc[3][1] = __builtin_amdgcn_mfma_f32_16x16x32_bf16(a3, b1, acc[3][1], 0, 0, 0);
                    acc[3][2] = __builtin_amdgcn_mfma_f32_16x16x32_bf16(a3, b2, acc[3][2], 0, 0, 0);
                    acc[3][3] = __builtin_amdgcn_mfma_f32_16x16x32_bf16(a3, b3, acc[3][3], 0, 0, 0);
                }
            }
        }

        // epilogue row h: C/D layout col(N)=lane&15, row(M)=quad*4+reg
        #pragma unroll
        for (int mt = 0; mt < 4; mt++) {
            const int o = wm + mt * 16 + quad * 4;
            #pragma unroll
            for (int nt = 0; nt < 4; nt++) {
                const int w = w0 + wn + nt * 16 + l15;
                float* op = out + (((size_t)(b * C_OUT + o) * HW + h) * HW + w);
                #pragma unroll
                for (int r = 0; r < 4; r++) op[(size_t)r * HW * HW] = acc[mt][nt][r];
            }
        }
    }
    #undef STAGE
}

// ---------------------------------------------------------------------------
// Legacy fallback (verified path) if workspace is too small for xT.
// ---------------------------------------------------------------------------
__global__ __launch_bounds__(256) void pool_kernel(const float* __restrict__ x,
                                                   float* __restrict__ pooled) {
    const int plane = blockIdx.x;
    const float4* p = (const float4*)(x + (size_t)plane * HW * HW);
    float s = 0.f;
    for (int idx = threadIdx.x; idx < (HW * HW) / 4; idx += 256) {
        float4 v = p[idx];
        s += v.x + v.y + v.z + v.w;
    }
    #pragma unroll
    for (int off = 32; off > 0; off >>= 1) s += __shfl_down(s, off, 64);
    __shared__ float ls[4];
    const int lane = threadIdx.x & 63, wv = threadIdx.x >> 6;
    if (lane == 0) ls[wv] = s;
    __syncthreads();
    if (threadIdx.x == 0) {
        float t = ls[0] + ls[1] + ls[2] + ls[3];
        pooled[plane] = t * (1.0f / (HW * HW));
    }
}

__global__ void attn_legacy(const float* __restrict__ pooled,
                            const float* __restrict__ attn_w,
                            const float* __restrict__ attn_b,
                            float* __restrict__ attn) {
    const int t = threadIdx.x;
    const int b = t >> 3, n = t & 7;
    float s = attn_b[n];
    #pragma unroll 8
    for (int c = 0; c < C_IN; c++) s += pooled[b * C_IN + c] * attn_w[n * C_IN + c];
    __shared__ float logits[B_ * NK];
    logits[t] = s;
    __syncthreads();
    float m = -1e30f;
    #pragma unroll
    for (int j = 0; j < NK; j++) m = fmaxf(m, logits[b * NK + j]);
    float denom = 0.f;
    #pragma unroll
    for (int j = 0; j < NK; j++) denom += expf(logits[b * NK + j] - m);
    attn[t] = expf(s - m) / denom;
}

__global__ __launch_bounds__(256) void conv_mfma(const float* __restrict__ x,
                                                 const short* __restrict__ Wt2,
                                                 float* __restrict__ out) {
    const int w0 = blockIdx.x * 128;
    const int h  = blockIdx.y;
    const int b  = blockIdx.z;
    const int t    = threadIdx.x;
    const int lane = t & 63;
    const int wid  = t >> 6;
    const int wm   = (wid & 1) * 64;
    const int wn   = (wid >> 1) * 64;
    const int l15  = lane & 15;
    const int quad = lane >> 4;
    __shared__ short sxs[130 * 72];
    f32x4 acc[4][4];
    #pragma unroll
    for (int mt = 0; mt < 4; mt++)
        #pragma unroll
        for (int nt = 0; nt < 4; nt++)
            acc[mt][nt] = (f32x4){0.f, 0.f, 0.f, 0.f};
    for (int kh = 0; kh < 3; kh++) {
        __syncthreads();
        const int hr = h + kh - 1;
        const bool rv = (hr >= 0) && (hr < HW);
        {
            const int wl = t & 127;
            const int w  = w0 + wl - 1;
            const bool wvalid = rv && (w >= 0) && (w < HW);
            #pragma unroll
            for (int it = 0; it < 16; it++) {
                const int ip = it * 2 + (t >> 7);
                float v0 = 0.f, v1 = 0.f;
                if (wvalid) {
                    const float* px = x + (((size_t)(b * C_IN + 2 * ip) * HW + hr) * HW + w);
                    v0 = px[0];
                    v1 = px[HW * HW];
                }
                ushort2 u;
                u.x = f2bf(v0);
                u.y = f2bf(v1);
                *(ushort2*)&sxs[wl * 72 + 2 * ip] = u;
            }
            if (t < 128) {
                const int i2  = t >> 1;
                const int wl2 = 128 + (t & 1);
                const int w2  = w0 + wl2 - 1;
                unsigned short uv = 0;
                if (rv && w2 < HW)
                    uv = f2bf(x[((size_t)(b * C_IN + i2) * HW + hr) * HW + w2]);
                ((unsigned short*)sxs)[wl2 * 72 + i2] = uv;
            }
        }
        __syncthreads();
        const short* wbase = Wt2 + (size_t)((b * 3 + kh) * 3) * 2 * 4096;
        #pragma unroll
        for (int kw = 0; kw < 3; kw++) {
            #pragma unroll
            for (int ic = 0; ic < 2; ic++) {
                const short* Ap = wbase + (size_t)(kw * 2 + ic) * 4096
                                + (wm + l15) * 32 + quad * 8;
                bf16x8 a0 = *(const bf16x8*)(Ap);
                bf16x8 a1 = *(const bf16x8*)(Ap + 512);
                bf16x8 a2 = *(const bf16x8*)(Ap + 1024);
                bf16x8 a3 = *(const bf16x8*)(Ap + 1536);
                const short* Bp = sxs + (wn + l15 + kw) * 72 + ic * 32 + quad * 8;
                bf16x8 b0 = *(const bf16x8*)(Bp);
                bf16x8 b1 = *(const bf16x8*)(Bp + 16 * 72);
                bf16x8 b2 = *(const bf16x8*)(Bp + 32 * 72);
                bf16x8 b3 = *(const bf16x8*)(Bp + 48 * 72);
                acc[0][0] = __builtin_amdgcn_mfma_f32_16x16x32_bf16(a0, b0, acc[0][0], 0, 0, 0);
                acc[0][1] = __builtin_amdgcn_mfma_f32_16x16x32_bf16(a0, b1, acc[0][1], 0, 0, 0);
                acc[0][2] = __builtin_amdgcn_mfma_f32_16x16x32_bf16(a0, b2, acc[0][2], 0, 0, 0);
                acc[0][3] = __builtin_amdgcn_mfma_f32_16x16x32_bf16(a0, b3, acc[0][3], 0, 0, 0);
                acc[1][0] = __builtin_amdgcn_mfma_f32_16x16x32_bf16(a1, b0, acc[1][0], 0, 0, 0);
                acc[1][1] = __builtin_amdgcn_mfma_f32_16x16x32_bf16(a1, b1, acc[1][1], 0, 0, 0);
                acc[1][2] = __builtin_amdgcn_mfma_f32_16x16x32_bf16(a1, b2, acc[1][2], 0, 0, 0);
                acc[1][3] = __builtin_amdgcn_mfma_f32_16x16x32_bf16(a1, b3, acc[1][3], 0, 0, 0);
                acc[2][0] = __builtin_amdgcn_mfma_f32_16x16x32_bf16(a2, b0, acc[2][0], 0, 0, 0);
                acc[2][1] = __builtin_amdgcn_mfma_f32_16x16x32_bf16(a2, b1, acc[2][1], 0, 0, 0);
                acc[2][2] = __builtin_amdgcn_mfma_f32_16x16x32_bf16(a2, b2, acc[2][2], 0, 0, 0);
                acc[2][3] = __builtin_amdgcn_mfma_f32_16x16x32_bf16(a2, b3, acc[2][3], 0, 0, 0);
                acc[3][0] = __builtin_amdgcn_mfma_f32_16x16x32_bf16(a3, b0, acc[3][0], 0, 0, 0);
                acc[3][1] = __builtin_amdgcn_mfma_f32_16x16x32_bf16(a3, b1, acc[3][1], 0, 0, 0);
                acc[3][2] = __builtin_amdgcn_mfma_f32_16x16x32_bf16(a3, b2, acc[3][2], 0, 0, 0);
                acc[3][3] = __builtin_amdgcn_mfma_f32_16x16x32_bf16(a3, b3, acc[3][3], 0, 0, 0);
            }
        }
    }
    #pragma unroll
    for (int mt = 0; mt < 4; mt++) {
        const int o = wm + mt * 16 + quad * 4;
        #pragma unroll
        for (int nt = 0; nt < 4; nt++) {
            const int w = w0 + wn + nt * 16 + l15;
            float* op = out + (((size_t)(b * C_OUT + o) * HW + h) * HW + w);
            #pragma unroll
            for (int r = 0; r < 4; r++) op[(size_t)r * HW * HW] = acc[mt][nt][r];
        }
    }
}

// ---------------------------------------------------------------------------
extern "C" void kernel_launch(void* const* d_in, const int* in_sizes, int n_in,
                              void* d_out, int out_size, void* d_ws, size_t ws_size,
                              hipStream_t stream) {
    const float* x      = (const float*)d_in[0];   // (8,64,256,256)
    const float* bank   = (const float*)d_in[1];   // (8,128,64,3,3)
    const float* attn_w = (const float*)d_in[2];   // (8,64)
    const float* attn_b = (const float*)d_in[3];   // (8,)
    float* out = (float*)d_out;                    // (8,128,256,256)

    const size_t XT_BYTES  = (size_t)B_ * 258 * XT_PLANE * sizeof(short);        // 68,175,360
    const size_t WT2_BYTES = (size_t)B_ * C_OUT * C_IN * KS * KS * sizeof(short); // 1,179,648
    const size_t PP_BYTES  = (size_t)B_ * 258 * 64 * sizeof(float);               // 528,384
    const size_t NEED = XT_BYTES + WT2_BYTES + PP_BYTES + (size_t)(B_ * NK) * 4 + 256;

    if (ws_size >= NEED) {
        unsigned short* xT  = (unsigned short*)d_ws;
        unsigned short* Wt2 = (unsigned short*)((char*)d_ws + XT_BYTES);
        float* poolpart = (float*)((char*)d_ws + XT_BYTES + WT2_BYTES);
        float* attn     = poolpart + (size_t)B_ * 258 * 64;

        prepass_kernel<<<dim3(258, B_), 256, 0, stream>>>(x, xT, poolpart);
        attn_kernel<<<B_, 256, 0, stream>>>(poolpart, attn_w, attn_b, attn);
        mix_kernel<<<(B_ * C_OUT * C_IN * KS * KS) / 256, 256, 0, stream>>>(bank, attn, Wt2);
        conv_mfma2<<<dim3(2, HW / 8, B_), 256, 0, stream>>>(xT, (const short*)Wt2, out);
    } else {
        // legacy verified path
        unsigned short* Wt2 = (unsigned short*)d_ws;
        float* pooled = (float*)((char*)d_ws + 589824 * sizeof(short));
        float* attn   = pooled + B_ * C_IN;
        pool_kernel<<<B_ * C_IN, 256, 0, stream>>>(x, pooled);
        attn_legacy<<<1, 64, 0, stream>>>(pooled, attn_w, attn_b, attn);
        mix_kernel<<<(B_ * C_OUT * C_IN * KS * KS) / 256, 256, 0, stream>>>(bank, attn, Wt2);
        conv_mfma<<<dim3(2, HW, B_), 256, 0, stream>>>(x, (const short*)Wt2, out);
    }
}

// Round 10
// 474.351 us; speedup vs baseline: 1.1534x; 1.0040x over previous
//
#include <hip/hip_runtime.h>
#include <hip/hip_bf16.h>

#define B_     8
#define C_IN   64
#define C_OUT  128
#define HW     256
#define NK     8
#define KS     3

typedef __attribute__((ext_vector_type(8))) short bf16x8;
typedef __attribute__((ext_vector_type(4))) float f32x4;
typedef __attribute__((ext_vector_type(4))) unsigned int u32x4;

__device__ inline unsigned short f2bf(float f) {
    union { float f; unsigned int u; } a; a.f = f;
    unsigned int u = a.u;
    u += 0x7fffu + ((u >> 16) & 1u);   // round-to-nearest-even
    return (unsigned short)(u >> 16);
}
__device__ inline float bf2f(unsigned short u) {
    union { float f; unsigned int u; } a; a.u = ((unsigned int)u) << 16; return a.f;
}
// packed RNE f32x2 -> bf16x2 via hardware v_cvt_pk_bf16_f32 (bit-identical
// to the manual f2bf pair, 1 instr instead of ~8) -- verified R8
__device__ inline unsigned int f2bf_pk(float lo, float hi) {
    float2 f2; f2.x = lo; f2.y = hi;
    __hip_bfloat162 bb = __float22bfloat162_rn(f2);
    unsigned int p;
    __builtin_memcpy(&p, &bb, 4);
    return p;
}

// xT geometry: [b][hp=258][r=258][c=64] bf16, hp = h+1, r = w+1, zero-padded
// borders. Within each 128-B row the 16-B chunk holding channels 8j..8j+7 is
// stored at slot (j ^ (r & 7)) -> conv's ds_read_b128 is bank-balanced while
// global_load_lds stays a linear copy (swizzle pre-baked in global memory).
#define XT_PLANE  (258 * 64)            /* shorts per (b,hp) plane */
#define SLAB_B    16640                 /* bytes per staged slab: 130 rows x 128 B */

// ---------------------------------------------------------------------------
// Prepass v3: float4-vectorized loads (16 x dwordx4/thread instead of 64
// scalar dwords), fp32-register pooling, LDS 33.8 -> 16.6 KB (2x occupancy).
// Decomposition: group g = t>>6 owns channels 16g..16g+15; lane l = t&63
// owns w = 4l..4l+3. Swizzled xT stores unchanged (8 x 16 B per thread).
// grid (258, 8) x 256.
// ---------------------------------------------------------------------------
__global__ __launch_bounds__(256) void prepass_kernel(const float* __restrict__ x,
                                                      unsigned short* __restrict__ xT,
                                                      float* __restrict__ poolpart) {
    const int hp = blockIdx.x;          // 0..257
    const int b  = blockIdx.y;
    const int t  = threadIdx.x;
    unsigned short* plane = xT + ((size_t)b * 258 + hp) * XT_PLANE;

    if (hp == 0 || hp == 257) {         // h-halo planes: all zero
        f32x4 z = {0.f, 0.f, 0.f, 0.f};
        for (int ofs = t * 16; ofs < XT_PLANE * 2; ofs += 256 * 16)
            *(f32x4*)((char*)plane + ofs) = z;
        return;
    }
    const int h = hp - 1;
    const int g = t >> 6;               // channel group 0..3
    const int l = t & 63;               // w-quad index

    __shared__ float tileS[64][65];     // [c][lane] fp32 partial sums (pad 65)

    // 16 coalesced float4 loads: channel 16g+ci, w = 4l..4l+3
    const float* xp = x + ((size_t)(b * C_IN + 16 * g) * HW + h) * HW + 4 * l;
    float4 va[16];
    #pragma unroll
    for (int ci = 0; ci < 16; ci++)
        va[ci] = *(const float4*)(xp + (size_t)ci * (HW * HW));

    // pool partials (fp32, pre-rounding): per-channel sum over this thread's 4 w
    #pragma unroll
    for (int ci = 0; ci < 16; ci++)
        tileS[16 * g + ci][l] = (va[ci].x + va[ci].y) + (va[ci].z + va[ci].w);

    // cvt + swizzled stores: per w-offset k, rows r = 4l+k+1
    #pragma unroll
    for (int k = 0; k < 4; k++) {
        unsigned int p[8];
        #pragma unroll
        for (int cp = 0; cp < 8; cp++) {
            const float lo = ((const float*)&va[2 * cp])[k];
            const float hi = ((const float*)&va[2 * cp + 1])[k];
            p[cp] = f2bf_pk(lo, hi);    // ch {16g+2cp, 16g+2cp+1}
        }
        const int r = 4 * l + k + 1;
        unsigned short* rowp = plane + (size_t)r * 64;
        const int sw = r & 7;
        u32x4 v0; v0[0] = p[0]; v0[1] = p[1]; v0[2] = p[2]; v0[3] = p[3];   // chunk j=2g
        u32x4 v1; v1[0] = p[4]; v1[1] = p[5]; v1[2] = p[6]; v1[3] = p[7];   // chunk j=2g+1
        *(u32x4*)(rowp + (size_t)(((2 * g)     ^ sw) * 8)) = v0;
        *(u32x4*)(rowp + (size_t)(((2 * g + 1) ^ sw) * 8)) = v1;
    }
    if (t < 2) {                        // w-halo rows r=0 and r=257: zero
        unsigned short* zr = plane + (size_t)(t ? 257 : 0) * 64;
        f32x4 z = {0.f, 0.f, 0.f, 0.f};
        #pragma unroll
        for (int j = 0; j < 8; j++) *(f32x4*)((char*)zr + j * 16) = z;
    }

    __syncthreads();
    if (t < 64) {                       // reduce over 64 lanes -> channel t
        float s = 0.f;
        #pragma unroll 8
        for (int i = 0; i < 64; i++) s += tileS[t][i];
        poolpart[((size_t)b * 258 + hp) * 64 + t] = s;
    }
}

// ---------------------------------------------------------------------------
// Pool-reduce + logits + softmax.  grid B_ blocks x 256 threads.
// ---------------------------------------------------------------------------
__global__ __launch_bounds__(256) void attn_kernel(const float* __restrict__ poolpart,
                                                   const float* __restrict__ attn_w,
                                                   const float* __restrict__ attn_b,
                                                   float* __restrict__ attn) {
    const int b = blockIdx.x;
    const int t = threadIdx.x;
    const int c = t & 63, part = t >> 6;
    __shared__ float psum[4][64];
    __shared__ float pooled[64];
    __shared__ float logits[NK];

    float s = 0.f;
    const float* pp = poolpart + ((size_t)b * 258) * 64 + c;
    for (int hp = part * 64 + 1; hp <= part * 64 + 64; hp++)
        s += pp[(size_t)hp * 64];
    psum[part][c] = s;
    __syncthreads();
    if (t < 64)
        pooled[t] = ((psum[0][t] + psum[1][t]) + (psum[2][t] + psum[3][t]))
                    * (1.0f / (HW * HW));
    __syncthreads();
    if (t < NK) {
        float l = attn_b[t];
        #pragma unroll 8
        for (int cc = 0; cc < C_IN; cc++) l += pooled[cc] * attn_w[t * C_IN + cc];
        logits[t] = l;
    }
    __syncthreads();
    if (t < NK) {
        float m = -1e30f;
        #pragma unroll
        for (int j = 0; j < NK; j++) m = fmaxf(m, logits[j]);
        float denom = 0.f;
        #pragma unroll
        for (int j = 0; j < NK; j++) denom += expf(logits[j] - m);
        attn[b * NK + t] = expf(logits[t] - m) / denom;
    }
}

// ---------------------------------------------------------------------------
// mixed weights -> bf16, pre-swizzled into MFMA A-fragment order:
//   Wt2[b][kh][kw][ic][o][di]  (ic = i>>5, di = i&31)
// ---------------------------------------------------------------------------
__global__ __launch_bounds__(256) void mix_kernel(const float* __restrict__ bank,
                                                  const float* __restrict__ attn,
                                                  unsigned short* __restrict__ Wt2) {
    const int PER_B = C_OUT * C_IN * KS * KS;   // 73728
    int idx = blockIdx.x * 256 + threadIdx.x;
    int b = idx / PER_B;
    int r = idx % PER_B;
    float s = 0.f;
    #pragma unroll
    for (int n = 0; n < NK; n++) s += attn[b * NK + n] * bank[(size_t)n * PER_B + r];
    int kw = r % 3;
    int t1 = r / 3;
    int kh = t1 % 3;
    int t2 = t1 / 3;
    int i = t2 & 63;
    int o = t2 >> 6;
    size_t off = (((size_t)((b * 3 + kh) * 3 + kw) * 2 + (i >> 5)) * 128 + o) * 32 + (i & 31);
    Wt2[off] = f2bf(s);
}

// ---------------------------------------------------------------------------
// Conv v2 (round-1 best-measured configuration, byte-exact): implicit GEMM,
// 8 output rows / block, 4-slab LDS ring fed by global_load_lds, vmcnt(5),
// raw barriers, swizzled ds_read_b128.
// grid (2 w-halves, 32 h-tiles, 8 b), block = 256 (4 waves, 2x2 of 64x64).
// ---------------------------------------------------------------------------
__global__ __launch_bounds__(256, 2) void conv_mfma2(const unsigned short* __restrict__ xT,
                                                     const short* __restrict__ Wt2,
                                                     float* __restrict__ out) {
    const int w0 = blockIdx.x * 128;
    const int h0 = blockIdx.y * 8;
    const int b  = blockIdx.z;
    const int t    = threadIdx.x;
    const int lane = t & 63;
    const int wid  = t >> 6;
    const int wm   = (wid & 1) * 64;   // wave M offset
    const int wn   = (wid >> 1) * 64;  // wave N offset
    const int l15  = lane & 15;
    const int quad = lane >> 4;

    __shared__ short sxs[4 * 8320];     // 4 ring slabs x 16640 B

    #define STAGE(HP) do {                                                            \
        const char* _src = (const char*)(xT + (((size_t)b * 258 + (size_t)(HP)) * 258 \
                                               + (size_t)w0) * 64);                   \
        char* _dst = (char*)sxs + (((HP) & 3) * SLAB_B);                              \
        const int _wo = wid * 4096;                                                   \
        __builtin_amdgcn_global_load_lds((const __attribute__((address_space(1))) void*)(_src + _wo +        lane * 16), (__attribute__((address_space(3))) void*)(_dst + _wo),        16, 0, 0); \
        __builtin_amdgcn_global_load_lds((const __attribute__((address_space(1))) void*)(_src + _wo + 1024 + lane * 16), (__attribute__((address_space(3))) void*)(_dst + _wo + 1024), 16, 0, 0); \
        __builtin_amdgcn_global_load_lds((const __attribute__((address_space(1))) void*)(_src + _wo + 2048 + lane * 16), (__attribute__((address_space(3))) void*)(_dst + _wo + 2048), 16, 0, 0); \
        __builtin_amdgcn_global_load_lds((const __attribute__((address_space(1))) void*)(_src + _wo + 3072 + lane * 16), (__attribute__((address_space(3))) void*)(_dst + _wo + 3072), 16, 0, 0); \
        __builtin_amdgcn_global_load_lds((const __attribute__((address_space(1))) void*)(_src + 16384 + lane * 4),       (__attribute__((address_space(3))) void*)(_dst + 16384),        4, 0, 0); \
    } while (0)

    const short* wt_b = Wt2 + (size_t)b * (9 * 2 * 4096);

    STAGE(h0); STAGE(h0 + 1); STAGE(h0 + 2);

    #pragma unroll 1
    for (int h = h0; h < h0 + 8; ++h) {
        __builtin_amdgcn_s_barrier();               // all readers of slab (h+3)&3 done
        if (h <= h0 + 6) {
            STAGE(h + 3);                           // prefetch next row, stays in flight
            asm volatile("s_waitcnt vmcnt(5)" ::: "memory");   // slab h+2 (and older) done
        } else {
            asm volatile("s_waitcnt vmcnt(0)" ::: "memory");
        }
        __builtin_amdgcn_s_barrier();               // all waves' slab portions visible

        f32x4 acc[4][4];
        #pragma unroll
        for (int mt = 0; mt < 4; mt++)
            #pragma unroll
            for (int nt = 0; nt < 4; nt++)
                acc[mt][nt] = (f32x4){0.f, 0.f, 0.f, 0.f};

        #pragma unroll
        for (int kh = 0; kh < 3; kh++) {
            const short* buf = sxs + ((h + kh) & 3) * 8320;
            const short* wbase = wt_b + kh * (3 * 2 * 4096);
            #pragma unroll
            for (int kw = 0; kw < 3; kw++) {
                const int row = wn + l15 + kw;      // LDS row == xT row mod 8 (w0%8==0)
                const int rx  = row & 7;
                #pragma unroll
                for (int ic = 0; ic < 2; ic++) {
                    const short* Ap = wbase + (kw * 2 + ic) * 4096 + (wm + l15) * 32 + quad * 8;
                    bf16x8 a0 = *(const bf16x8*)(Ap);
                    bf16x8 a1 = *(const bf16x8*)(Ap + 512);
                    bf16x8 a2 = *(const bf16x8*)(Ap + 1024);
                    bf16x8 a3 = *(const bf16x8*)(Ap + 1536);
                    // rows +16/+32/+48 share (row&7): one swizzled base serves all 4
                    const short* Bp = buf + row * 64 + (((ic << 2) + quad) ^ rx) * 8;
                    bf16x8 b0 = *(const bf16x8*)(Bp);
                    bf16x8 b1 = *(const bf16x8*)(Bp + 1024);
                    bf16x8 b2 = *(const bf16x8*)(Bp + 2048);
                    bf16x8 b3 = *(const bf16x8*)(Bp + 3072);
                    acc[0][0] = __builtin_amdgcn_mfma_f32_16x16x32_bf16(a0, b0, acc[0][0], 0, 0, 0);
                    acc[0][1] = __builtin_amdgcn_mfma_f32_16x16x32_bf16(a0, b1, acc[0][1], 0, 0, 0);
                    acc[0][2] = __builtin_amdgcn_mfma_f32_16x16x32_bf16(a0, b2, acc[0][2], 0, 0, 0);
                    acc[0][3] = __builtin_amdgcn_mfma_f32_16x16x32_bf16(a0, b3, acc[0][3], 0, 0, 0);
                    acc[1][0] = __builtin_amdgcn_mfma_f32_16x16x32_bf16(a1, b0, acc[1][0], 0, 0, 0);
                    acc[1][1] = __builtin_amdgcn_mfma_f32_16x16x32_bf16(a1, b1, acc[1][1], 0, 0, 0);
                    acc[1][2] = __builtin_amdgcn_mfma_f32_16x16x32_bf16(a1, b2, acc[1][2], 0, 0, 0);
                    acc[1][3] = __builtin_amdgcn_mfma_f32_16x16x32_bf16(a1, b3, acc[1][3], 0, 0, 0);
                    acc[2][0] = __builtin_amdgcn_mfma_f32_16x16x32_bf16(a2, b0, acc[2][0], 0, 0, 0);
                    acc[2][1] = __builtin_amdgcn_mfma_f32_16x16x32_bf16(a2, b1, acc[2][1], 0, 0, 0);
                    acc[2][2] = __builtin_amdgcn_mfma_f32_16x16x32_bf16(a2, b2, acc[2][2], 0, 0, 0);
                    acc[2][3] = __builtin_amdgcn_mfma_f32_16x16x32_bf16(a2, b3, acc[2][3], 0, 0, 0);
                    acc[3][0] = __builtin_amdgcn_mfma_f32_16x16x32_bf16(a3, b0, acc[3][0], 0, 0, 0);
                    acc[3][1] = __builtin_amdgcn_mfma_f32_16x16x32_bf16(a3, b1, acc[3][1], 0, 0, 0);
                    acc[3][2] = __builtin_amdgcn_mfma_f32_16x16x32_bf16(a3, b2, acc[3][2], 0, 0, 0);
                    acc[3][3] = __builtin_amdgcn_mfma_f32_16x16x32_bf16(a3, b3, acc[3][3], 0, 0, 0);
                }
            }
        }

        // epilogue row h: C/D layout col(N)=lane&15, row(M)=quad*4+reg
        #pragma unroll
        for (int mt = 0; mt < 4; mt++) {
            const int o = wm + mt * 16 + quad * 4;
            #pragma unroll
            for (int nt = 0; nt < 4; nt++) {
                const int w = w0 + wn + nt * 16 + l15;
                float* op = out + (((size_t)(b * C_OUT + o) * HW + h) * HW + w);
                #pragma unroll
                for (int r = 0; r < 4; r++) op[(size_t)r * HW * HW] = acc[mt][nt][r];
            }
        }
    }
    #undef STAGE
}

// ---------------------------------------------------------------------------
// Legacy fallback (verified path) if workspace is too small for xT.
// ---------------------------------------------------------------------------
__global__ __launch_bounds__(256) void pool_kernel(const float* __restrict__ x,
                                                   float* __restrict__ pooled) {
    const int plane = blockIdx.x;
    const float4* p = (const float4*)(x + (size_t)plane * HW * HW);
    float s = 0.f;
    for (int idx = threadIdx.x; idx < (HW * HW) / 4; idx += 256) {
        float4 v = p[idx];
        s += v.x + v.y + v.z + v.w;
    }
    #pragma unroll
    for (int off = 32; off > 0; off >>= 1) s += __shfl_down(s, off, 64);
    __shared__ float ls[4];
    const int lane = threadIdx.x & 63, wv = threadIdx.x >> 6;
    if (lane == 0) ls[wv] = s;
    __syncthreads();
    if (threadIdx.x == 0) {
        float t = ls[0] + ls[1] + ls[2] + ls[3];
        pooled[plane] = t * (1.0f / (HW * HW));
    }
}

__global__ void attn_legacy(const float* __restrict__ pooled,
                            const float* __restrict__ attn_w,
                            const float* __restrict__ attn_b,
                            float* __restrict__ attn) {
    const int t = threadIdx.x;
    const int b = t >> 3, n = t & 7;
    float s = attn_b[n];
    #pragma unroll 8
    for (int c = 0; c < C_IN; c++) s += pooled[b * C_IN + c] * attn_w[n * C_IN + c];
    __shared__ float logits[B_ * NK];
    logits[t] = s;
    __syncthreads();
    float m = -1e30f;
    #pragma unroll
    for (int j = 0; j < NK; j++) m = fmaxf(m, logits[b * NK + j]);
    float denom = 0.f;
    #pragma unroll
    for (int j = 0; j < NK; j++) denom += expf(logits[b * NK + j] - m);
    attn[t] = expf(s - m) / denom;
}

__global__ __launch_bounds__(256) void conv_mfma(const float* __restrict__ x,
                                                 const short* __restrict__ Wt2,
                                                 float* __restrict__ out) {
    const int w0 = blockIdx.x * 128;
    const int h  = blockIdx.y;
    const int b  = blockIdx.z;
    const int t    = threadIdx.x;
    const int lane = t & 63;
    const int wid  = t >> 6;
    const int wm   = (wid & 1) * 64;
    const int wn   = (wid >> 1) * 64;
    const int l15  = lane & 15;
    const int quad = lane >> 4;
    __shared__ short sxs[130 * 72];
    f32x4 acc[4][4];
    #pragma unroll
    for (int mt = 0; mt < 4; mt++)
        #pragma unroll
        for (int nt = 0; nt < 4; nt++)
            acc[mt][nt] = (f32x4){0.f, 0.f, 0.f, 0.f};
    for (int kh = 0; kh < 3; kh++) {
        __syncthreads();
        const int hr = h + kh - 1;
        const bool rv = (hr >= 0) && (hr < HW);
        {
            const int wl = t & 127;
            const int w  = w0 + wl - 1;
            const bool wvalid = rv && (w >= 0) && (w < HW);
            #pragma unroll
            for (int it = 0; it < 16; it++) {
                const int ip = it * 2 + (t >> 7);
                float v0 = 0.f, v1 = 0.f;
                if (wvalid) {
                    const float* px = x + (((size_t)(b * C_IN + 2 * ip) * HW + hr) * HW + w);
                    v0 = px[0];
                    v1 = px[HW * HW];
                }
                ushort2 u;
                u.x = f2bf(v0);
                u.y = f2bf(v1);
                *(ushort2*)&sxs[wl * 72 + 2 * ip] = u;
            }
            if (t < 128) {
                const int i2  = t >> 1;
                const int wl2 = 128 + (t & 1);
                const int w2  = w0 + wl2 - 1;
                unsigned short uv = 0;
                if (rv && w2 < HW)
                    uv = f2bf(x[((size_t)(b * C_IN + i2) * HW + hr) * HW + w2]);
                ((unsigned short*)sxs)[wl2 * 72 + i2] = uv;
            }
        }
        __syncthreads();
        const short* wbase = Wt2 + (size_t)((b * 3 + kh) * 3) * 2 * 4096;
        #pragma unroll
        for (int kw = 0; kw < 3; kw++) {
            #pragma unroll
            for (int ic = 0; ic < 2; ic++) {
                const short* Ap = wbase + (size_t)(kw * 2 + ic) * 4096
                                + (wm + l15) * 32 + quad * 8;
                bf16x8 a0 = *(const bf16x8*)(Ap);
                bf16x8 a1 = *(const bf16x8*)(Ap + 512);
                bf16x8 a2 = *(const bf16x8*)(Ap + 1024);
                bf16x8 a3 = *(const bf16x8*)(Ap + 1536);
                const short* Bp = sxs + (wn + l15 + kw) * 72 + ic * 32 + quad * 8;
                bf16x8 b0 = *(const bf16x8*)(Bp);
                bf16x8 b1 = *(const bf16x8*)(Bp + 16 * 72);
                bf16x8 b2 = *(const bf16x8*)(Bp + 32 * 72);
                bf16x8 b3 = *(const bf16x8*)(Bp + 48 * 72);
                acc[0][0] = __builtin_amdgcn_mfma_f32_16x16x32_bf16(a0, b0, acc[0][0], 0, 0, 0);
                acc[0][1] = __builtin_amdgcn_mfma_f32_16x16x32_bf16(a0, b1, acc[0][1], 0, 0, 0);
                acc[0][2] = __builtin_amdgcn_mfma_f32_16x16x32_bf16(a0, b2, acc[0][2], 0, 0, 0);
                acc[0][3] = __builtin_amdgcn_mfma_f32_16x16x32_bf16(a0, b3, acc[0][3], 0, 0, 0);
                acc[1][0] = __builtin_amdgcn_mfma_f32_16x16x32_bf16(a1, b0, acc[1][0], 0, 0, 0);
                acc[1][1] = __builtin_amdgcn_mfma_f32_16x16x32_bf16(a1, b1, acc[1][1], 0, 0, 0);
                acc[1][2] = __builtin_amdgcn_mfma_f32_16x16x32_bf16(a1, b2, acc[1][2], 0, 0, 0);
                acc[1][3] = __builtin_amdgcn_mfma_f32_16x16x32_bf16(a1, b3, acc[1][3], 0, 0, 0);
                acc[2][0] = __builtin_amdgcn_mfma_f32_16x16x32_bf16(a2, b0, acc[2][0], 0, 0, 0);
                acc[2][1] = __builtin_amdgcn_mfma_f32_16x16x32_bf16(a2, b1, acc[2][1], 0, 0, 0);
                acc[2][2] = __builtin_amdgcn_mfma_f32_16x16x32_bf16(a2, b2, acc[2][2], 0, 0, 0);
                acc[2][3] = __builtin_amdgcn_mfma_f32_16x16x32_bf16(a2, b3, acc[2][3], 0, 0, 0);
                acc[3][0] = __builtin_amdgcn_mfma_f32_16x16x32_bf16(a3, b0, acc[3][0], 0, 0, 0);
                acc[3][1] = __builtin_amdgcn_mfma_f32_16x16x32_bf16(a3, b1, acc[3][1], 0, 0, 0);
                acc[3][2] = __builtin_amdgcn_mfma_f32_16x16x32_bf16(a3, b2, acc[3][2], 0, 0, 0);
                acc[3][3] = __builtin_amdgcn_mfma_f32_16x16x32_bf16(a3, b3, acc[3][3], 0, 0, 0);
            }
        }
    }
    #pragma unroll
    for (int mt = 0; mt < 4; mt++) {
        const int o = wm + mt * 16 + quad * 4;
        #pragma unroll
        for (int nt = 0; nt < 4; nt++) {
            const int w = w0 + wn + nt * 16 + l15;
            float* op = out + (((size_t)(b * C_OUT + o) * HW + h) * HW + w);
            #pragma unroll
            for (int r = 0; r < 4; r++) op[(size_t)r * HW * HW] = acc[mt][nt][r];
        }
    }
}

// ---------------------------------------------------------------------------
extern "C" void kernel_launch(void* const* d_in, const int* in_sizes, int n_in,
                              void* d_out, int out_size, void* d_ws, size_t ws_size,
                              hipStream_t stream) {
    const float* x      = (const float*)d_in[0];   // (8,64,256,256)
    const float* bank   = (const float*)d_in[1];   // (8,128,64,3,3)
    const float* attn_w = (const float*)d_in[2];   // (8,64)
    const float* attn_b = (const float*)d_in[3];   // (8,)
    float* out = (float*)d_out;                    // (8,128,256,256)

    const size_t XT_BYTES  = (size_t)B_ * 258 * XT_PLANE * sizeof(short);        // 68,175,360
    const size_t WT2_BYTES = (size_t)B_ * C_OUT * C_IN * KS * KS * sizeof(short); // 1,179,648
    const size_t PP_BYTES  = (size_t)B_ * 258 * 64 * sizeof(float);               // 528,384
    const size_t NEED = XT_BYTES + WT2_BYTES + PP_BYTES + (size_t)(B_ * NK) * 4 + 256;

    if (ws_size >= NEED) {
        unsigned short* xT  = (unsigned short*)d_ws;
        unsigned short* Wt2 = (unsigned short*)((char*)d_ws + XT_BYTES);
        float* poolpart = (float*)((char*)d_ws + XT_BYTES + WT2_BYTES);
        float* attn     = poolpart + (size_t)B_ * 258 * 64;

        prepass_kernel<<<dim3(258, B_), 256, 0, stream>>>(x, xT, poolpart);
        attn_kernel<<<B_, 256, 0, stream>>>(poolpart, attn_w, attn_b, attn);
        mix_kernel<<<(B_ * C_OUT * C_IN * KS * KS) / 256, 256, 0, stream>>>(bank, attn, Wt2);
        conv_mfma2<<<dim3(2, HW / 8, B_), 256, 0, stream>>>(xT, (const short*)Wt2, out);
    } else {
        // legacy verified path
        unsigned short* Wt2 = (unsigned short*)d_ws;
        float* pooled = (float*)((char*)d_ws + 589824 * sizeof(short));
        float* attn   = pooled + B_ * C_IN;
        pool_kernel<<<B_ * C_IN, 256, 0, stream>>>(x, pooled);
        attn_legacy<<<1, 64, 0, stream>>>(pooled, attn_w, attn_b, attn);
        mix_kernel<<<(B_ * C_OUT * C_IN * KS * KS) / 256, 256, 0, stream>>>(bank, attn, Wt2);
        conv_mfma<<<dim3(2, HW, B_), 256, 0, stream>>>(x, (const short*)Wt2, out);
    }
}